// Round 1
// baseline (1684.369 us; speedup 1.0000x reference)
//
#include <hip/hip_runtime.h>

// ---------------------------------------------------------------------------
// MolNet layer, restructured:
//   Phase A: deg/dis, per-node precompute PC/PR (hoisted edge matmuls),
//            folded weight products A_i = Wv2v_top@Wvl_top, A_j = Wv2v_bot@Wvl_top
//   Phase B: per-edge kernel (1 wave = 1 edge, lane = channel):
//            gathers + silu/tanh + RBF K=50 dot + atomic scatter of
//            norm*ss, norm*vs, norm*rel_d*t, norm*vector[row], norm
//   Phase C: per-node finalize: postponed matmuls Wsl, Wvl_bot, A_j, A_i
// ---------------------------------------------------------------------------

__device__ __forceinline__ float silu_f(float x) { return x / (1.0f + __expf(-x)); }
// tanh(x) = 1 - 2/(1+e^{2x}); safe at +/-inf
__device__ __forceinline__ float tanh_f(float x) { return 1.0f - 2.0f / (1.0f + __expf(2.0f * x)); }

__global__ __launch_bounds__(256) void deg_k(const int* __restrict__ ei,
                                             const float* __restrict__ attr,
                                             float* __restrict__ deg, int E) {
    int e = blockIdx.x * 256 + threadIdx.x;
    if (e < E) atomicAdd(&deg[ei[E + e]], attr[e]);
}

__global__ __launch_bounds__(256) void dis_k(const float* __restrict__ deg,
                                             float* __restrict__ dis, int N) {
    int n = blockIdx.x * 256 + threadIdx.x;
    if (n < N) {
        float d = deg[n];
        dis[n] = (d > 0.0f) ? rsqrtf(d) : 0.0f;
    }
}

// A_i[k][c] = sum_m Wv2v[k][m]   * Wvl[m][c]   (col side of vv, through Wvl_top)
// A_j[k][c] = sum_m Wv2v[64+k][m]* Wvl[m][c]   (row side of vv, through Wvl_top)
__global__ void aiaj_k(const float* __restrict__ Wv2v, const float* __restrict__ Wvl,
                       float* __restrict__ Ai, float* __restrict__ Aj) {
    int k = blockIdx.x;      // 64 blocks
    int c = threadIdx.x;     // 64 threads
    float ai = 0.0f, aj = 0.0f;
    for (int m = 0; m < 64; ++m) {
        float w = Wvl[m * 64 + c];
        ai += Wv2v[k * 64 + m] * w;
        aj += Wv2v[(64 + k) * 64 + m] * w;
    }
    Ai[k * 64 + c] = ai;
    Aj[k * 64 + c] = aj;
}

// Per-node precompute: one wave per node, lane = channel.
// PC[n] = { scalar@Ws2s_top + bs2s | scalar@Ws2v_top + bs2v | vn@Wv2s_rows0 + bv2s }
// PR[n] = { scalar@Ws2s_bot        | scalar@Ws2v_bot        | vn@Wv2s_rows1        }
__global__ __launch_bounds__(256) void node_pre_k(
    const float* __restrict__ scalar, const float* __restrict__ vec,
    const float* __restrict__ Ws2s, const float* __restrict__ Ws2v,
    const float* __restrict__ Wv2s, const float* __restrict__ bs2s,
    const float* __restrict__ bs2v, const float* __restrict__ bv2s,
    float* __restrict__ PC, float* __restrict__ PR, int N) {
    const int lane = threadIdx.x & 63;
    const int n = (blockIdx.x * 256 + threadIdx.x) >> 6;
    if (n >= N) return;
    float s  = scalar[n * 64 + lane];
    float v0 = vec[n * 192 + lane];
    float v1 = vec[n * 192 + 64 + lane];
    float v2 = vec[n * 192 + 128 + lane];
    float vn = sqrtf(v0 * v0 + v1 * v1 + v2 * v2);
    float p1 = bs2s[lane], p3 = bs2v[lane], p5 = bv2s[lane];
    float p2 = 0.0f, p4 = 0.0f, p6 = 0.0f;
#pragma unroll 8
    for (int k = 0; k < 64; ++k) {
        float xs = __shfl(s, k);
        float xv = __shfl(vn, k);
        p1 += xs * Ws2s[k * 64 + lane];
        p2 += xs * Ws2s[(64 + k) * 64 + lane];
        p3 += xs * Ws2v[k * 64 + lane];
        p4 += xs * Ws2v[(64 + k) * 64 + lane];
        p5 += xv * Wv2s[k * 64 + lane];
        p6 += xv * Wv2s[(64 + k) * 64 + lane];
    }
    PC[n * 192 + lane]       = p1;
    PC[n * 192 + 64 + lane]  = p3;
    PC[n * 192 + 128 + lane] = p5;
    PR[n * 192 + lane]       = p2;
    PR[n * 192 + 64 + lane]  = p4;
    PR[n * 192 + 128 + lane] = p6;
}

// Per-edge kernel: one wave per edge (grid-stride), lane = channel.
__global__ __launch_bounds__(256) void edge_k(
    const int* __restrict__ ei, const float* __restrict__ attr,
    const float* __restrict__ pos, const float* __restrict__ dis,
    const float* __restrict__ PC, const float* __restrict__ PR,
    const float* __restrict__ vec, const float* __restrict__ Wv2s,
    float* __restrict__ agg1, float* __restrict__ agg2,
    float* __restrict__ B3, float* __restrict__ Bv,
    float* __restrict__ Wsum, int E) {
    __shared__ float sWr[50 * 64];  // rbf rows of Wv2s (rows 128..177)
    for (int i = threadIdx.x; i < 50 * 64; i += 256) sWr[i] = Wv2s[128 * 64 + i];
    __syncthreads();

    const int lane = threadIdx.x & 63;
    const int waveInBlock = threadIdx.x >> 6;
    const int totWaves = gridDim.x * 4;
    const float coeff = -48.02f;  // -0.5/(5/49)^2 == -2401/50

    for (int e = blockIdx.x * 4 + waveInBlock; e < E; e += totWaves) {
        const int row = ei[e];
        const int col = ei[E + e];
        const float nrm = dis[row] * dis[col] * attr[e];

        const float r0 = pos[col * 3 + 0] - pos[row * 3 + 0];
        const float r1 = pos[col * 3 + 1] - pos[row * 3 + 1];
        const float r2 = pos[col * 3 + 2] - pos[row * 3 + 2];
        const float dist = sqrtf(r0 * r0 + r1 * r1 + r2 * r2);

        // lane l < 50 computes gaussian l; then all-lane dot with Wr column
        float g = 0.0f;
        if (lane < 50) {
            float dl = dist - 0.10204081632653061f * (float)lane;  // 5*l/49
            g = __expf(coeff * dl * dl);
        }
        float rbfw = 0.0f;
#pragma unroll
        for (int l = 0; l < 50; ++l) rbfw += __shfl(g, l) * sWr[l * 64 + lane];

        const int cb = col * 192, rb = row * 192;
        const float ss = silu_f(PC[cb + lane] + PR[rb + lane]);
        const float tt = tanh_f(PC[cb + 64 + lane] + PR[rb + 64 + lane]);
        const float vs = silu_f(PC[cb + 128 + lane] + PR[rb + 128 + lane] + rbfw);

        atomicAdd(&agg1[col * 64 + lane], nrm * ss);
        atomicAdd(&agg2[col * 64 + lane], nrm * vs);
        if (lane == 0) atomicAdd(&Wsum[col], nrm);

        const float nt = nrm * tt;
        float v = vec[rb + lane];
        atomicAdd(&Bv[cb + lane], nrm * v);
        atomicAdd(&B3[cb + lane], nt * r0);
        v = vec[rb + 64 + lane];
        atomicAdd(&Bv[cb + 64 + lane], nrm * v);
        atomicAdd(&B3[cb + 64 + lane], nt * r1);
        v = vec[rb + 128 + lane];
        atomicAdd(&Bv[cb + 128 + lane], nrm * v);
        atomicAdd(&B3[cb + 128 + lane], nt * r2);
    }
}

// Per-node finalize: postponed matmuls + residuals. One wave per node.
__global__ __launch_bounds__(256) void finalize_k(
    const float* __restrict__ scalar, const float* __restrict__ vec,
    const float* __restrict__ Wsl, const float* __restrict__ bsl,
    const float* __restrict__ Wvl, const float* __restrict__ Ai,
    const float* __restrict__ Aj, const float* __restrict__ agg2,
    const float* __restrict__ B3, const float* __restrict__ Bv,
    const float* __restrict__ Wsum, float* __restrict__ outs,
    float* __restrict__ outv, int N) {
    const int lane = threadIdx.x & 63;
    const int n = (blockIdx.x * 256 + threadIdx.x) >> 6;
    if (n >= N) return;
    const float wsn = Wsum[n];

    // scalar path: agg_s = AGG1@Wsl_top + AGG2@Wsl_bot + Wsum*bsl
    float A1 = outs[n * 64 + lane];  // AGG1 was accumulated into d_out scalar region
    float A2 = agg2[n * 64 + lane];
    float acc = wsn * bsl[lane];
#pragma unroll 8
    for (int k = 0; k < 64; ++k) {
        acc += __shfl(A1, k) * Wsl[k * 64 + lane];
        acc += __shfl(A2, k) * Wsl[(64 + k) * 64 + lane];
    }
    outs[n * 64 + lane] = silu_f(acc) + scalar[n * 64 + lane];

    // vector path: agg_v[d] = B3[d]@Wvl_bot + Bv[d]@A_j + Wsum*(vector[d]@A_i)
#pragma unroll
    for (int d = 0; d < 3; ++d) {
        float b3 = B3[n * 192 + d * 64 + lane];
        float bv = Bv[n * 192 + d * 64 + lane];
        float vv = vec[n * 192 + d * 64 + lane];
        float a3 = 0.0f, av = 0.0f, ai = 0.0f;
#pragma unroll 8
        for (int k = 0; k < 64; ++k) {
            a3 += __shfl(b3, k) * Wvl[(64 + k) * 64 + lane];
            av += __shfl(bv, k) * Aj[k * 64 + lane];
            ai += __shfl(vv, k) * Ai[k * 64 + lane];
        }
        outv[n * 192 + d * 64 + lane] = a3 + av + wsn * ai + vv;
    }
}

extern "C" void kernel_launch(void* const* d_in, const int* in_sizes, int n_in,
                              void* d_out, int out_size, void* d_ws, size_t ws_size,
                              hipStream_t stream) {
    const float* scalar    = (const float*)d_in[0];
    const float* vector    = (const float*)d_in[1];
    const float* position  = (const float*)d_in[2];
    const int*   edge_index= (const int*)d_in[3];
    const float* edge_attr = (const float*)d_in[4];
    const float* Ws2s      = (const float*)d_in[5];
    const float* bs2s      = (const float*)d_in[6];
    const float* Wv2s      = (const float*)d_in[7];
    const float* bv2s      = (const float*)d_in[8];
    const float* Wsl       = (const float*)d_in[9];
    const float* bsl       = (const float*)d_in[10];
    const float* Ws2v      = (const float*)d_in[11];
    const float* bs2v      = (const float*)d_in[12];
    const float* Wv2v      = (const float*)d_in[13];
    const float* Wvl       = (const float*)d_in[14];

    const int N = in_sizes[0] / 64;
    const int E = in_sizes[3] / 2;

    float* ws   = (float*)d_ws;
    float* deg  = ws;                        // N
    float* Wsum = deg + N;                   // N
    float* AGG2 = Wsum + N;                  // 64N
    float* B3   = AGG2 + (size_t)64 * N;     // 192N
    float* Bv   = B3 + (size_t)192 * N;      // 192N
    // ---- zero region ends: 450N floats ----
    float* dis  = Bv + (size_t)192 * N;      // N
    float* PC   = dis + N;                   // 192N
    float* PR   = PC + (size_t)192 * N;      // 192N
    float* Ai   = PR + (size_t)192 * N;      // 4096
    float* Aj   = Ai + 4096;                 // 4096

    float* outs = (float*)d_out;             // N*64 (also AGG1 accumulator)
    float* outv = outs + (size_t)N * 64;     // N*192

    hipMemsetAsync(d_ws, 0, sizeof(float) * (size_t)450 * N, stream);
    hipMemsetAsync(d_out, 0, sizeof(float) * (size_t)out_size, stream);

    deg_k<<<(E + 255) / 256, 256, 0, stream>>>(edge_index, edge_attr, deg, E);
    dis_k<<<(N + 255) / 256, 256, 0, stream>>>(deg, dis, N);
    aiaj_k<<<64, 64, 0, stream>>>(Wv2v, Wvl, Ai, Aj);
    node_pre_k<<<(N + 3) / 4, 256, 0, stream>>>(scalar, vector, Ws2s, Ws2v, Wv2s,
                                                bs2s, bs2v, bv2s, PC, PR, N);
    edge_k<<<2048, 256, 0, stream>>>(edge_index, edge_attr, position, dis, PC, PR,
                                     vector, Wv2s, outs, AGG2, B3, Bv, Wsum, E);
    finalize_k<<<(N + 3) / 4, 256, 0, stream>>>(scalar, vector, Wsl, bsl, Wvl, Ai, Aj,
                                                AGG2, B3, Bv, Wsum, outs, outv, N);
}

// Round 2
// 922.087 us; speedup vs baseline: 1.8267x; 1.8267x over previous
//
#include <hip/hip_runtime.h>

// ---------------------------------------------------------------------------
// MolNet layer, round 2: counting-sort edges by destination col, then
// per-col register accumulation with plain stores (no big atomics), and a
// piecewise-linear lookup table for the RBF@Wv2s_rbf product.
//
// Pipeline:
//   memset(deg, cnt) -> deg_cnt_k -> dis_k -> scan_k (1 block) ->
//   scatter_k (srow/sna into sorted order) -> node_pre_k -> rbf_table_k ->
//   aiaj_k -> edge_sorted_k -> finalize_k
// ---------------------------------------------------------------------------

__device__ __forceinline__ float silu_f(float x) { return x / (1.0f + __expf(-x)); }
__device__ __forceinline__ float tanh_f(float x) { return 1.0f - 2.0f / (1.0f + __expf(2.0f * x)); }

__global__ __launch_bounds__(256) void deg_cnt_k(const int* __restrict__ ei,
                                                 const float* __restrict__ attr,
                                                 float* __restrict__ deg,
                                                 int* __restrict__ cnt, int E) {
    int e = blockIdx.x * 256 + threadIdx.x;
    if (e < E) {
        int col = ei[E + e];
        atomicAdd(&deg[col], attr[e]);
        atomicAdd(&cnt[col], 1);
    }
}

__global__ __launch_bounds__(256) void dis_k(const float* __restrict__ deg,
                                             float* __restrict__ dis, int N) {
    int n = blockIdx.x * 256 + threadIdx.x;
    if (n < N) {
        float d = deg[n];
        dis[n] = (d > 0.0f) ? rsqrtf(d) : 0.0f;
    }
}

// Exclusive prefix sum of cnt -> offA and offB (two copies; offA is consumed
// as a cursor by scatter_k, offB is preserved for edge_sorted_k).
__global__ __launch_bounds__(1024) void scan_k(const int* __restrict__ cnt,
                                               int* __restrict__ offA,
                                               int* __restrict__ offB, int N) {
    __shared__ int tmp[1024];
    __shared__ int carry;
    if (threadIdx.x == 0) { carry = 0; offA[0] = 0; offB[0] = 0; }
    __syncthreads();
    for (int base = 0; base < N; base += 1024) {
        int i = base + threadIdx.x;
        int v = (i < N) ? cnt[i] : 0;
        tmp[threadIdx.x] = v;
        __syncthreads();
        for (int s = 1; s < 1024; s <<= 1) {
            int t = (threadIdx.x >= s) ? tmp[threadIdx.x - s] : 0;
            __syncthreads();
            tmp[threadIdx.x] += t;
            __syncthreads();
        }
        int inc = carry + tmp[threadIdx.x];
        if (i < N) { offA[i + 1] = inc; offB[i + 1] = inc; }
        __syncthreads();
        if (threadIdx.x == 1023) carry = inc;
        __syncthreads();
    }
}

// Scatter edges into col-sorted order; pre-fold dis[row]*attr into sna.
__global__ __launch_bounds__(256) void scatter_k(const int* __restrict__ ei,
                                                 const float* __restrict__ attr,
                                                 const float* __restrict__ dis,
                                                 int* __restrict__ offA,
                                                 int* __restrict__ srow,
                                                 float* __restrict__ sna, int E) {
    int e = blockIdx.x * 256 + threadIdx.x;
    if (e < E) {
        int row = ei[e];
        int col = ei[E + e];
        int p = atomicAdd(&offA[col], 1);
        srow[p] = row;
        sna[p] = dis[row] * attr[e];
    }
}

// Table: T[s][c] = sum_l exp(coeff*(s*step - o_l)^2) * Wv2s[(128+l)*64 + c]
// 1025 rows covering d in [0, 6]; beyond 6 the true value is ~exp(-48)~0.
__global__ __launch_bounds__(256) void rbf_table_k(const float* __restrict__ Wv2s,
                                                   float* __restrict__ T) {
    int idx = blockIdx.x * 256 + threadIdx.x;
    if (idx >= 1025 * 64) return;
    int s = idx >> 6, c = idx & 63;
    float d = (float)s * (6.0f / 1024.0f);
    float acc = 0.0f;
    for (int l = 0; l < 50; ++l) {
        float dl = d - 0.10204081632653061f * (float)l;
        acc += __expf(-48.02f * dl * dl) * Wv2s[(128 + l) * 64 + c];
    }
    T[idx] = acc;
}

// Folded weight products: Ai = Wv2v_top @ Wvl_top, Aj = Wv2v_bot @ Wvl_top
__global__ void aiaj_k(const float* __restrict__ Wv2v, const float* __restrict__ Wvl,
                       float* __restrict__ Ai, float* __restrict__ Aj) {
    int k = blockIdx.x, c = threadIdx.x;
    float ai = 0.0f, aj = 0.0f;
    for (int m = 0; m < 64; ++m) {
        float w = Wvl[m * 64 + c];
        ai += Wv2v[k * 64 + m] * w;
        aj += Wv2v[(64 + k) * 64 + m] * w;
    }
    Ai[k * 64 + c] = ai;
    Aj[k * 64 + c] = aj;
}

// Per-node precompute, 4 nodes per wave (weight loads amortized 4x).
// PC[n] = { s@Ws2s_top + bs2s | s@Ws2v_top + bs2v | vn@Wv2s_top + bv2s }
// PR[n] = { s@Ws2s_bot        | s@Ws2v_bot        | vn@Wv2s_bot         }
__global__ __launch_bounds__(256) void node_pre_k(
    const float* __restrict__ scalar, const float* __restrict__ vec,
    const float* __restrict__ Ws2s, const float* __restrict__ Ws2v,
    const float* __restrict__ Wv2s, const float* __restrict__ bs2s,
    const float* __restrict__ bs2v, const float* __restrict__ bv2s,
    float* __restrict__ PC, float* __restrict__ PR, int N) {
    const int lane = threadIdx.x & 63;
    const int wave = (blockIdx.x * 256 + threadIdx.x) >> 6;
    const int n0 = wave * 4;
    if (n0 >= N) return;
    float s[4], vn[4];
#pragma unroll
    for (int j = 0; j < 4; ++j) {
        int n = min(n0 + j, N - 1);
        s[j] = scalar[(size_t)n * 64 + lane];
        float v0 = vec[(size_t)n * 192 + lane];
        float v1 = vec[(size_t)n * 192 + 64 + lane];
        float v2 = vec[(size_t)n * 192 + 128 + lane];
        vn[j] = sqrtf(v0 * v0 + v1 * v1 + v2 * v2);
    }
    float p1[4], p2[4], p3[4], p4[4], p5[4], p6[4];
#pragma unroll
    for (int j = 0; j < 4; ++j) {
        p1[j] = bs2s[lane]; p3[j] = bs2v[lane]; p5[j] = bv2s[lane];
        p2[j] = 0.0f; p4[j] = 0.0f; p6[j] = 0.0f;
    }
#pragma unroll 4
    for (int k = 0; k < 64; ++k) {
        float w1 = Ws2s[k * 64 + lane];
        float w2 = Ws2s[(64 + k) * 64 + lane];
        float w3 = Ws2v[k * 64 + lane];
        float w4 = Ws2v[(64 + k) * 64 + lane];
        float w5 = Wv2s[k * 64 + lane];
        float w6 = Wv2s[(64 + k) * 64 + lane];
#pragma unroll
        for (int j = 0; j < 4; ++j) {
            float xs = __shfl(s[j], k);
            float xv = __shfl(vn[j], k);
            p1[j] += xs * w1; p2[j] += xs * w2;
            p3[j] += xs * w3; p4[j] += xs * w4;
            p5[j] += xv * w5; p6[j] += xv * w6;
        }
    }
#pragma unroll
    for (int j = 0; j < 4; ++j) {
        int n = n0 + j;
        if (n >= N) break;
        size_t b = (size_t)n * 192;
        PC[b + lane] = p1[j]; PC[b + 64 + lane] = p3[j]; PC[b + 128 + lane] = p5[j];
        PR[b + lane] = p2[j]; PR[b + 64 + lane] = p4[j]; PR[b + 128 + lane] = p6[j];
    }
}

// Edge kernel over col-sorted edges: one wave owns CPW consecutive cols,
// accumulates in registers, plain-stores per col. No atomics.
#define CPW 4
__global__ __launch_bounds__(256) void edge_sorted_k(
    const float* __restrict__ pos, const float* __restrict__ dis,
    const float* __restrict__ PC, const float* __restrict__ PR,
    const float* __restrict__ vec, const float* __restrict__ T,
    const int* __restrict__ srow, const float* __restrict__ sna,
    const int* __restrict__ offB,
    float* __restrict__ AGG1, float* __restrict__ AGG2,
    float* __restrict__ B3, float* __restrict__ Bv,
    float* __restrict__ Wsum, int N) {
    const int lane = threadIdx.x & 63;
    const int wave = (blockIdx.x * 256 + threadIdx.x) >> 6;
    const int c0 = wave * CPW;
    const int cend = min(c0 + CPW, N);
    for (int col = c0; col < cend; ++col) {
        const int e0 = offB[col], e1 = offB[col + 1];
        const float dcol = dis[col];
        const float px = pos[col * 3], py = pos[col * 3 + 1], pz = pos[col * 3 + 2];
        const size_t cb = (size_t)col * 192;
        const float pc0 = PC[cb + lane], pc1 = PC[cb + 64 + lane], pc2 = PC[cb + 128 + lane];
        float a1 = 0, a2 = 0, wsum = 0;
        float b30 = 0, b31 = 0, b32 = 0, bv0 = 0, bv1 = 0, bv2 = 0;
        for (int e = e0; e < e1; ++e) {
            const int row = srow[e];
            const float nrm = dcol * sna[e];
            const size_t rb = (size_t)row * 192;
            const float r0 = px - pos[row * 3 + 0];
            const float r1 = py - pos[row * 3 + 1];
            const float r2 = pz - pos[row * 3 + 2];
            const float dist = sqrtf(r0 * r0 + r1 * r1 + r2 * r2);
            float t = fminf(dist * (1024.0f / 6.0f), 1023.0f);
            int s0 = (int)t;
            float f = t - (float)s0;
            float T0 = T[s0 * 64 + lane], T1 = T[s0 * 64 + 64 + lane];
            float rbfw = T0 + f * (T1 - T0);
            float ss = silu_f(pc0 + PR[rb + lane]);
            float tt = tanh_f(pc1 + PR[rb + 64 + lane]);
            float vs = silu_f(pc2 + PR[rb + 128 + lane] + rbfw);
            wsum += nrm;
            a1 += nrm * ss;
            a2 += nrm * vs;
            float nt = nrm * tt;
            b30 += nt * r0; b31 += nt * r1; b32 += nt * r2;
            bv0 += nrm * vec[rb + lane];
            bv1 += nrm * vec[rb + 64 + lane];
            bv2 += nrm * vec[rb + 128 + lane];
        }
        AGG1[(size_t)col * 64 + lane] = a1;
        AGG2[(size_t)col * 64 + lane] = a2;
        B3[cb + lane] = b30; B3[cb + 64 + lane] = b31; B3[cb + 128 + lane] = b32;
        Bv[cb + lane] = bv0; Bv[cb + 64 + lane] = bv1; Bv[cb + 128 + lane] = bv2;
        if (lane == 0) Wsum[col] = wsum;
    }
}

// Finalize, 2 nodes per wave. The Ai-stream folds Wsum into the vv operand so
// all three vector streams share one accumulator.
__global__ __launch_bounds__(256) void finalize_k(
    const float* __restrict__ scalar, const float* __restrict__ vec,
    const float* __restrict__ Wsl, const float* __restrict__ bsl,
    const float* __restrict__ Wvl, const float* __restrict__ Ai,
    const float* __restrict__ Aj, const float* __restrict__ agg2,
    const float* __restrict__ B3, const float* __restrict__ Bv,
    const float* __restrict__ Wsum, float* __restrict__ outs,
    float* __restrict__ outv, int N) {
    const int lane = threadIdx.x & 63;
    const int wave = (blockIdx.x * 256 + threadIdx.x) >> 6;
    const int n0 = wave * 2;
    if (n0 >= N) return;
    float A1[2], A2[2], wsn[2], acc[2];
#pragma unroll
    for (int j = 0; j < 2; ++j) {
        int n = min(n0 + j, N - 1);
        A1[j] = outs[(size_t)n * 64 + lane];
        A2[j] = agg2[(size_t)n * 64 + lane];
        wsn[j] = Wsum[n];
        acc[j] = wsn[j] * bsl[lane];
    }
#pragma unroll 4
    for (int k = 0; k < 64; ++k) {
        float w1 = Wsl[k * 64 + lane];
        float w2 = Wsl[(64 + k) * 64 + lane];
#pragma unroll
        for (int j = 0; j < 2; ++j) {
            acc[j] += __shfl(A1[j], k) * w1 + __shfl(A2[j], k) * w2;
        }
    }
#pragma unroll
    for (int j = 0; j < 2; ++j) {
        int n = n0 + j;
        if (n < N) outs[(size_t)n * 64 + lane] = silu_f(acc[j]) + scalar[(size_t)n * 64 + lane];
    }

    // vector path
    float b3[2][3], bv[2][3], vvs[2][3], vvo[2][3], av[2][3];
#pragma unroll
    for (int j = 0; j < 2; ++j) {
        int n = min(n0 + j, N - 1);
        size_t b = (size_t)n * 192;
#pragma unroll
        for (int d = 0; d < 3; ++d) {
            b3[j][d] = B3[b + d * 64 + lane];
            bv[j][d] = Bv[b + d * 64 + lane];
            vvo[j][d] = vec[b + d * 64 + lane];
            vvs[j][d] = wsn[j] * vvo[j][d];
            av[j][d] = 0.0f;
        }
    }
#pragma unroll 2
    for (int k = 0; k < 64; ++k) {
        float w3 = Wvl[(64 + k) * 64 + lane];
        float wj = Aj[k * 64 + lane];
        float wi = Ai[k * 64 + lane];
#pragma unroll
        for (int j = 0; j < 2; ++j) {
#pragma unroll
            for (int d = 0; d < 3; ++d) {
                av[j][d] += __shfl(b3[j][d], k) * w3
                          + __shfl(bv[j][d], k) * wj
                          + __shfl(vvs[j][d], k) * wi;
            }
        }
    }
#pragma unroll
    for (int j = 0; j < 2; ++j) {
        int n = n0 + j;
        if (n >= N) break;
        size_t b = (size_t)n * 192;
#pragma unroll
        for (int d = 0; d < 3; ++d) outv[b + d * 64 + lane] = av[j][d] + vvo[j][d];
    }
}

extern "C" void kernel_launch(void* const* d_in, const int* in_sizes, int n_in,
                              void* d_out, int out_size, void* d_ws, size_t ws_size,
                              hipStream_t stream) {
    const float* scalar     = (const float*)d_in[0];
    const float* vector     = (const float*)d_in[1];
    const float* position   = (const float*)d_in[2];
    const int*   edge_index = (const int*)d_in[3];
    const float* edge_attr  = (const float*)d_in[4];
    const float* Ws2s       = (const float*)d_in[5];
    const float* bs2s       = (const float*)d_in[6];
    const float* Wv2s       = (const float*)d_in[7];
    const float* bv2s       = (const float*)d_in[8];
    const float* Wsl        = (const float*)d_in[9];
    const float* bsl        = (const float*)d_in[10];
    const float* Ws2v       = (const float*)d_in[11];
    const float* bs2v       = (const float*)d_in[12];
    const float* Wv2v       = (const float*)d_in[13];
    const float* Wvl        = (const float*)d_in[14];

    const int N = in_sizes[0] / 64;
    const int E = in_sizes[3] / 2;
    const size_t sN = (size_t)N;

    float* W = (float*)d_ws;
    // layout (floats), with lifetime-based overlays:
    float* dis  = W;                         // N
    float* PC   = W + sN;                    // 192N  [overlay: cnt, offA before node_pre]
    int*   cnt  = (int*)(W + sN);            // N ints   (dead before PC written)
    int*   offA = (int*)(W + 2 * sN);        // N+1 ints (dead before PC written)
    float* PR   = W + 193 * sN;              // 192N
    float* AGG2 = W + 385 * sN;              // 64N   [overlay: deg before edge_sorted]
    float* deg  = W + 385 * sN;              // N floats (dead after dis_k)
    float* B3   = W + 449 * sN;              // 192N
    float* Wsum = W + 641 * sN;              // N
    int*   offB = (int*)(W + 642 * sN);      // N+1 ints
    float* Ai   = W + 644 * sN;              // 4096
    float* Aj   = Ai + 4096;                 // 4096
    float* Tb   = Aj + 4096;                 // 65600  (ends < 646N)
    int*   srow = (int*)(W + 646 * sN);      // E ints (E = 16N)
    float* sna  = W + 662 * sN;              // E floats -> total 678N floats (~108 MB)

    float* outs = (float*)d_out;             // 64N  (doubles as AGG1)
    float* outv = outs + 64 * sN;            // 192N (doubles as Bv accumulator)
    float* Bv   = outv;

    hipMemsetAsync(deg, 0, sizeof(float) * sN, stream);
    hipMemsetAsync(cnt, 0, sizeof(int) * sN, stream);

    deg_cnt_k<<<(E + 255) / 256, 256, 0, stream>>>(edge_index, edge_attr, deg, cnt, E);
    dis_k<<<(N + 255) / 256, 256, 0, stream>>>(deg, dis, N);
    scan_k<<<1, 1024, 0, stream>>>(cnt, offA, offB, N);
    scatter_k<<<(E + 255) / 256, 256, 0, stream>>>(edge_index, edge_attr, dis, offA, srow, sna, E);
    node_pre_k<<<(N / 4 + 3) / 4, 256, 0, stream>>>(scalar, vector, Ws2s, Ws2v, Wv2s,
                                                    bs2s, bs2v, bv2s, PC, PR, N);
    rbf_table_k<<<(1025 * 64 + 255) / 256, 256, 0, stream>>>(Wv2s, Tb);
    aiaj_k<<<64, 64, 0, stream>>>(Wv2v, Wvl, Ai, Aj);
    edge_sorted_k<<<((N + CPW - 1) / CPW + 3) / 4, 256, 0, stream>>>(
        position, dis, PC, PR, vector, Tb, srow, sna, offB, outs, AGG2, B3, Bv, Wsum, N);
    finalize_k<<<((N + 1) / 2 + 3) / 4, 256, 0, stream>>>(
        scalar, vector, Wsl, bsl, Wvl, Ai, Aj, AGG2, B3, Bv, Wsum, outs, outv, N);
}

// Round 3
// 729.302 us; speedup vs baseline: 2.3096x; 1.2643x over previous
//
#include <hip/hip_runtime.h>

// ---------------------------------------------------------------------------
// MolNet layer, round 3:
//  - counting-sort edges by destination col (3-phase parallel scan)
//  - edge kernel: per-col register accumulation, plain stores, RBF via LUT
//  - node_pre / finalize rewritten as lane-per-node GEMVs: acc[64] in VGPRs,
//    weight rows are wave-uniform (SGPR broadcast) -> no ds_bpermute at all.
// ---------------------------------------------------------------------------

__device__ __forceinline__ float silu_f(float x) { return x / (1.0f + __expf(-x)); }
__device__ __forceinline__ float tanh_f(float x) { return 1.0f - 2.0f / (1.0f + __expf(2.0f * x)); }

__global__ __launch_bounds__(256) void deg_cnt_k(const int* __restrict__ ei,
                                                 const float* __restrict__ attr,
                                                 float* __restrict__ deg,
                                                 int* __restrict__ cnt, int E) {
    int e = blockIdx.x * 256 + threadIdx.x;
    if (e < E) {
        int col = ei[E + e];
        atomicAdd(&deg[col], attr[e]);
        atomicAdd(&cnt[col], 1);
    }
}

__global__ __launch_bounds__(256) void dis_k(const float* __restrict__ deg,
                                             float* __restrict__ dis, int N) {
    int n = blockIdx.x * 256 + threadIdx.x;
    if (n < N) {
        float d = deg[n];
        dis[n] = (d > 0.0f) ? rsqrtf(d) : 0.0f;
    }
}

// ---- 3-phase exclusive scan of cnt[N] -> offA, offB -----------------------
__global__ __launch_bounds__(1024) void scan1_k(const int* __restrict__ cnt,
                                                int* __restrict__ blockSums, int N) {
    __shared__ int tmp[1024];
    int i = blockIdx.x * 1024 + threadIdx.x;
    tmp[threadIdx.x] = (i < N) ? cnt[i] : 0;
    __syncthreads();
    for (int s = 512; s > 0; s >>= 1) {
        if (threadIdx.x < s) tmp[threadIdx.x] += tmp[threadIdx.x + s];
        __syncthreads();
    }
    if (threadIdx.x == 0) blockSums[blockIdx.x] = tmp[0];
}

__global__ __launch_bounds__(64) void scan2_k(int* __restrict__ blockSums, int nb) {
    int t = threadIdx.x;
    int own = (t < nb) ? blockSums[t] : 0;
    int v = own;
    for (int s = 1; s < 64; s <<= 1) {
        int up = __shfl_up(v, s);
        if (t >= s) v += up;
    }
    if (t < nb) blockSums[t] = v - own;  // exclusive base per block
}

__global__ __launch_bounds__(1024) void scan3_k(const int* __restrict__ cnt,
                                                const int* __restrict__ blockSums,
                                                int* __restrict__ offA,
                                                int* __restrict__ offB, int N) {
    __shared__ int tmp[1024];
    int i = blockIdx.x * 1024 + threadIdx.x;
    tmp[threadIdx.x] = (i < N) ? cnt[i] : 0;
    __syncthreads();
    for (int s = 1; s < 1024; s <<= 1) {
        int t = (threadIdx.x >= s) ? tmp[threadIdx.x - s] : 0;
        __syncthreads();
        tmp[threadIdx.x] += t;
        __syncthreads();
    }
    if (i < N) {
        int off = blockSums[blockIdx.x] + tmp[threadIdx.x];
        offA[i + 1] = off;
        offB[i + 1] = off;
    }
    if (blockIdx.x == 0 && threadIdx.x == 0) { offA[0] = 0; offB[0] = 0; }
}

__global__ __launch_bounds__(256) void scatter_k(const int* __restrict__ ei,
                                                 const float* __restrict__ attr,
                                                 const float* __restrict__ dis,
                                                 int* __restrict__ offA,
                                                 int* __restrict__ srow,
                                                 float* __restrict__ sna, int E) {
    int e = blockIdx.x * 256 + threadIdx.x;
    if (e < E) {
        int row = ei[e];
        int col = ei[E + e];
        int p = atomicAdd(&offA[col], 1);
        srow[p] = row;
        sna[p] = dis[row] * attr[e];
    }
}

// RBF lookup table: T[s][c] = sum_l exp(-48.02*(s*step - o_l)^2) * Wv2s_rbf[l][c]
__global__ __launch_bounds__(256) void rbf_table_k(const float* __restrict__ Wv2s,
                                                   float* __restrict__ T) {
    int idx = blockIdx.x * 256 + threadIdx.x;
    if (idx >= 1025 * 64) return;
    int s = idx >> 6, c = idx & 63;
    float d = (float)s * (6.0f / 1024.0f);
    float acc = 0.0f;
    for (int l = 0; l < 50; ++l) {
        float dl = d - 0.10204081632653061f * (float)l;
        acc += __expf(-48.02f * dl * dl) * Wv2s[(128 + l) * 64 + c];
    }
    T[idx] = acc;
}

// Folded weight products: Ai = Wv2v_top @ Wvl_top, Aj = Wv2v_bot @ Wvl_top
__global__ void aiaj_k(const float* __restrict__ Wv2v, const float* __restrict__ Wvl,
                       float* __restrict__ Ai, float* __restrict__ Aj) {
    int k = blockIdx.x, c = threadIdx.x;
    float ai = 0.0f, aj = 0.0f;
    for (int m = 0; m < 64; ++m) {
        float w = Wvl[m * 64 + c];
        ai += Wv2v[k * 64 + m] * w;
        aj += Wv2v[(64 + k) * 64 + m] * w;
    }
    Ai[k * 64 + c] = ai;
    Aj[k * 64 + c] = aj;
}

// ---- node precompute: lane-per-node GEMV, 6 stream-chunks over blockIdx.y --
// y: 0 Ws2s_top+bs2s->PC0 | 1 Ws2s_bot->PR0 | 2 Ws2v_top+bs2v->PC1 |
//    3 Ws2v_bot->PR1      | 4 Wv2s_top+bv2s->PC2 | 5 Wv2s_bot->PR2
__global__ __launch_bounds__(256) void node_pre2_k(
    const float* __restrict__ scalar, const float* __restrict__ vec,
    const float* __restrict__ Ws2s, const float* __restrict__ Ws2v,
    const float* __restrict__ Wv2s, const float* __restrict__ bs2s,
    const float* __restrict__ bs2v, const float* __restrict__ bv2s,
    float* __restrict__ PC, float* __restrict__ PR, int N) {
    const int y = blockIdx.y;
    const int gid = blockIdx.x * 256 + threadIdx.x;
    const int n = (gid < N) ? gid : (N - 1);

    const float* Wb;
    const float* bias = nullptr;
    if      (y == 0) { Wb = Ws2s;        bias = bs2s; }
    else if (y == 1) { Wb = Ws2s + 4096; }
    else if (y == 2) { Wb = Ws2v;        bias = bs2v; }
    else if (y == 3) { Wb = Ws2v + 4096; }
    else if (y == 4) { Wb = Wv2s;        bias = bv2s; }
    else             { Wb = Wv2s + 4096; }
    const bool useS = (y < 4);

    float acc[64];
#pragma unroll
    for (int c = 0; c < 64; ++c) acc[c] = 0.0f;

    for (int kc = 0; kc < 4; ++kc) {
        float x[16];
        if (useS) {
#pragma unroll
            for (int q = 0; q < 4; ++q) {
                float4 t = *(const float4*)(scalar + (size_t)n * 64 + kc * 16 + q * 4);
                x[q * 4 + 0] = t.x; x[q * 4 + 1] = t.y;
                x[q * 4 + 2] = t.z; x[q * 4 + 3] = t.w;
            }
        } else {
#pragma unroll
            for (int q = 0; q < 4; ++q) {
                const float* vb = vec + (size_t)n * 192 + kc * 16 + q * 4;
                float4 a = *(const float4*)(vb);
                float4 b = *(const float4*)(vb + 64);
                float4 c4 = *(const float4*)(vb + 128);
                x[q * 4 + 0] = sqrtf(a.x * a.x + b.x * b.x + c4.x * c4.x);
                x[q * 4 + 1] = sqrtf(a.y * a.y + b.y * b.y + c4.y * c4.y);
                x[q * 4 + 2] = sqrtf(a.z * a.z + b.z * b.z + c4.z * c4.z);
                x[q * 4 + 3] = sqrtf(a.w * a.w + b.w * b.w + c4.w * c4.w);
            }
        }
#pragma unroll
        for (int kk = 0; kk < 16; ++kk) {
            const float* wr = Wb + (kc * 16 + kk) * 64;  // wave-uniform row
            const float xv = x[kk];
#pragma unroll
            for (int c = 0; c < 64; ++c) acc[c] += xv * wr[c];
        }
    }
    float* dst = ((y & 1) ? PR : PC) + (size_t)n * 192 + (y >> 1) * 64;
    if (gid < N) {
#pragma unroll
        for (int q = 0; q < 16; ++q) {
            float4 o;
            int c = q * 4;
            o.x = acc[c];     o.y = acc[c + 1];
            o.z = acc[c + 2]; o.w = acc[c + 3];
            if (bias) { o.x += bias[c]; o.y += bias[c + 1]; o.z += bias[c + 2]; o.w += bias[c + 3]; }
            *(float4*)(dst + c) = o;
        }
    }
}

// ---- edge kernel over col-sorted edges (unchanged from round 2) -----------
#define CPW 4
__global__ __launch_bounds__(256) void edge_sorted_k(
    const float* __restrict__ pos, const float* __restrict__ dis,
    const float* __restrict__ PC, const float* __restrict__ PR,
    const float* __restrict__ vec, const float* __restrict__ T,
    const int* __restrict__ srow, const float* __restrict__ sna,
    const int* __restrict__ offB,
    float* __restrict__ AGG1, float* __restrict__ AGG2,
    float* __restrict__ B3, float* __restrict__ Bv,
    float* __restrict__ Wsum, int N) {
    const int lane = threadIdx.x & 63;
    const int wave = (blockIdx.x * 256 + threadIdx.x) >> 6;
    const int c0 = wave * CPW;
    const int cend = min(c0 + CPW, N);
    for (int col = c0; col < cend; ++col) {
        const int e0 = offB[col], e1 = offB[col + 1];
        const float dcol = dis[col];
        const float px = pos[col * 3], py = pos[col * 3 + 1], pz = pos[col * 3 + 2];
        const size_t cb = (size_t)col * 192;
        const float pc0 = PC[cb + lane], pc1 = PC[cb + 64 + lane], pc2 = PC[cb + 128 + lane];
        float a1 = 0, a2 = 0, wsum = 0;
        float b30 = 0, b31 = 0, b32 = 0, bv0 = 0, bv1 = 0, bv2 = 0;
        for (int e = e0; e < e1; ++e) {
            const int row = srow[e];
            const float nrm = dcol * sna[e];
            const size_t rb = (size_t)row * 192;
            const float r0 = px - pos[row * 3 + 0];
            const float r1 = py - pos[row * 3 + 1];
            const float r2 = pz - pos[row * 3 + 2];
            const float dist = sqrtf(r0 * r0 + r1 * r1 + r2 * r2);
            float t = fminf(dist * (1024.0f / 6.0f), 1023.0f);
            int s0 = (int)t;
            float f = t - (float)s0;
            float T0 = T[s0 * 64 + lane], T1 = T[s0 * 64 + 64 + lane];
            float rbfw = T0 + f * (T1 - T0);
            float ss = silu_f(pc0 + PR[rb + lane]);
            float tt = tanh_f(pc1 + PR[rb + 64 + lane]);
            float vs = silu_f(pc2 + PR[rb + 128 + lane] + rbfw);
            wsum += nrm;
            a1 += nrm * ss;
            a2 += nrm * vs;
            float nt = nrm * tt;
            b30 += nt * r0; b31 += nt * r1; b32 += nt * r2;
            bv0 += nrm * vec[rb + lane];
            bv1 += nrm * vec[rb + 64 + lane];
            bv2 += nrm * vec[rb + 128 + lane];
        }
        AGG1[(size_t)col * 64 + lane] = a1;
        AGG2[(size_t)col * 64 + lane] = a2;
        B3[cb + lane] = b30; B3[cb + 64 + lane] = b31; B3[cb + 128 + lane] = b32;
        Bv[cb + lane] = bv0; Bv[cb + 64 + lane] = bv1; Bv[cb + 128 + lane] = bv2;
        if (lane == 0) Wsum[col] = wsum;
    }
}

// ---- finalize: lane-per-node GEMV, 4 chunks over blockIdx.y ---------------
// y==0: scalar path; y==1..3: vector path for d = y-1.
__global__ __launch_bounds__(256) void finalize2_k(
    const float* __restrict__ scalar, const float* __restrict__ vec,
    const float* __restrict__ Wsl, const float* __restrict__ bsl,
    const float* __restrict__ Wvl, const float* __restrict__ Ai,
    const float* __restrict__ Aj, const float* __restrict__ agg2,
    const float* __restrict__ B3, const float* __restrict__ Bv,
    const float* __restrict__ Wsum, float* __restrict__ outs,
    float* __restrict__ outv, int N) {
    const int y = blockIdx.y;
    const int gid = blockIdx.x * 256 + threadIdx.x;
    const int n = (gid < N) ? gid : (N - 1);
    const float wsn = Wsum[n];

    float acc[64];
#pragma unroll
    for (int c = 0; c < 64; ++c) acc[c] = 0.0f;

    if (y == 0) {
        const float* a1p = outs + (size_t)n * 64;   // AGG1 lives in outs
        const float* a2p = agg2 + (size_t)n * 64;
        for (int kc = 0; kc < 4; ++kc) {
            float a1[16], a2[16];
#pragma unroll
            for (int q = 0; q < 4; ++q) {
                float4 t1 = *(const float4*)(a1p + kc * 16 + q * 4);
                float4 t2 = *(const float4*)(a2p + kc * 16 + q * 4);
                a1[q * 4] = t1.x; a1[q * 4 + 1] = t1.y; a1[q * 4 + 2] = t1.z; a1[q * 4 + 3] = t1.w;
                a2[q * 4] = t2.x; a2[q * 4 + 1] = t2.y; a2[q * 4 + 2] = t2.z; a2[q * 4 + 3] = t2.w;
            }
#pragma unroll
            for (int kk = 0; kk < 16; ++kk) {
                const int k = kc * 16 + kk;
                const float* w1 = Wsl + k * 64;          // wave-uniform
                const float* w2 = Wsl + (64 + k) * 64;   // wave-uniform
                const float x1 = a1[kk], x2 = a2[kk];
#pragma unroll
                for (int c = 0; c < 64; ++c) acc[c] += x1 * w1[c] + x2 * w2[c];
            }
        }
        if (gid < N) {
#pragma unroll
            for (int q = 0; q < 16; ++q) {
                int c = q * 4;
                float4 sc = *(const float4*)(scalar + (size_t)n * 64 + c);
                float4 o;
                o.x = silu_f(acc[c]     + wsn * bsl[c])     + sc.x;
                o.y = silu_f(acc[c + 1] + wsn * bsl[c + 1]) + sc.y;
                o.z = silu_f(acc[c + 2] + wsn * bsl[c + 2]) + sc.z;
                o.w = silu_f(acc[c + 3] + wsn * bsl[c + 3]) + sc.w;
                *(float4*)(outs + (size_t)n * 64 + c) = o;
            }
        }
    } else {
        const int d = y - 1;
        const size_t base = (size_t)n * 192 + d * 64;
        const float* b3p = B3 + base;
        const float* bvp = Bv + base;
        const float* vvp = vec + base;
        for (int kc = 0; kc < 4; ++kc) {
            float b3[16], bv[16], vs[16];
#pragma unroll
            for (int q = 0; q < 4; ++q) {
                float4 t1 = *(const float4*)(b3p + kc * 16 + q * 4);
                float4 t2 = *(const float4*)(bvp + kc * 16 + q * 4);
                float4 t3 = *(const float4*)(vvp + kc * 16 + q * 4);
                b3[q * 4] = t1.x; b3[q * 4 + 1] = t1.y; b3[q * 4 + 2] = t1.z; b3[q * 4 + 3] = t1.w;
                bv[q * 4] = t2.x; bv[q * 4 + 1] = t2.y; bv[q * 4 + 2] = t2.z; bv[q * 4 + 3] = t2.w;
                vs[q * 4] = wsn * t3.x; vs[q * 4 + 1] = wsn * t3.y;
                vs[q * 4 + 2] = wsn * t3.z; vs[q * 4 + 3] = wsn * t3.w;
            }
#pragma unroll
            for (int kk = 0; kk < 16; ++kk) {
                const int k = kc * 16 + kk;
                const float* w3 = Wvl + (64 + k) * 64;   // wave-uniform
                const float* wj = Aj + k * 64;           // wave-uniform
                const float* wi = Ai + k * 64;           // wave-uniform
                const float x3 = b3[kk], xj = bv[kk], xi = vs[kk];
#pragma unroll
                for (int c = 0; c < 64; ++c)
                    acc[c] += x3 * w3[c] + xj * wj[c] + xi * wi[c];
            }
        }
        if (gid < N) {
#pragma unroll
            for (int q = 0; q < 16; ++q) {
                int c = q * 4;
                float4 vv = *(const float4*)(vvp + c);
                float4 o;
                o.x = acc[c] + vv.x; o.y = acc[c + 1] + vv.y;
                o.z = acc[c + 2] + vv.z; o.w = acc[c + 3] + vv.w;
                *(float4*)(outv + base + c) = o;
            }
        }
    }
}

extern "C" void kernel_launch(void* const* d_in, const int* in_sizes, int n_in,
                              void* d_out, int out_size, void* d_ws, size_t ws_size,
                              hipStream_t stream) {
    const float* scalar     = (const float*)d_in[0];
    const float* vector     = (const float*)d_in[1];
    const float* position   = (const float*)d_in[2];
    const int*   edge_index = (const int*)d_in[3];
    const float* edge_attr  = (const float*)d_in[4];
    const float* Ws2s       = (const float*)d_in[5];
    const float* bs2s       = (const float*)d_in[6];
    const float* Wv2s       = (const float*)d_in[7];
    const float* bv2s       = (const float*)d_in[8];
    const float* Wsl        = (const float*)d_in[9];
    const float* bsl        = (const float*)d_in[10];
    const float* Ws2v       = (const float*)d_in[11];
    const float* bs2v       = (const float*)d_in[12];
    const float* Wv2v       = (const float*)d_in[13];
    const float* Wvl        = (const float*)d_in[14];

    const int N = in_sizes[0] / 64;
    const int E = in_sizes[3] / 2;
    const size_t sN = (size_t)N;
    const int nb = (N + 1023) / 1024;

    float* W = (float*)d_ws;
    float* dis  = W;                         // N
    float* PC   = W + sN;                    // 192N [overlay: cnt, offA pre-node_pre]
    int*   cnt  = (int*)(W + sN);            // N ints
    int*   offA = (int*)(W + 2 * sN);        // N+1 ints
    float* PR   = W + 193 * sN;              // 192N
    float* AGG2 = W + 385 * sN;              // 64N [overlay: deg pre-edge]
    float* deg  = W + 385 * sN;              // N floats
    float* B3   = W + 449 * sN;              // 192N
    float* Wsum = W + 641 * sN;              // N
    int*   offB = (int*)(W + 642 * sN);      // N+1 ints
    float* Ai   = W + 644 * sN;              // 4096
    float* Aj   = Ai + 4096;                 // 4096
    float* Tb   = Aj + 4096;                 // 65600 [overlay: blockSums during scan]
    int*   blockSums = (int*)Tb;             // nb ints (dead before rbf_table_k)
    int*   srow = (int*)(W + 646 * sN);      // E ints
    float* sna  = W + 662 * sN;              // E floats

    float* outs = (float*)d_out;             // 64N (doubles as AGG1)
    float* outv = outs + 64 * sN;            // 192N (doubles as Bv accumulator)
    float* Bv   = outv;

    hipMemsetAsync(deg, 0, sizeof(float) * sN, stream);
    hipMemsetAsync(cnt, 0, sizeof(int) * sN, stream);

    deg_cnt_k<<<(E + 255) / 256, 256, 0, stream>>>(edge_index, edge_attr, deg, cnt, E);
    dis_k<<<(N + 255) / 256, 256, 0, stream>>>(deg, dis, N);
    scan1_k<<<nb, 1024, 0, stream>>>(cnt, blockSums, N);
    scan2_k<<<1, 64, 0, stream>>>(blockSums, nb);
    scan3_k<<<nb, 1024, 0, stream>>>(cnt, blockSums, offA, offB, N);
    scatter_k<<<(E + 255) / 256, 256, 0, stream>>>(edge_index, edge_attr, dis, offA, srow, sna, E);
    node_pre2_k<<<dim3((N + 255) / 256, 6), 256, 0, stream>>>(
        scalar, vector, Ws2s, Ws2v, Wv2s, bs2s, bs2v, bv2s, PC, PR, N);
    rbf_table_k<<<(1025 * 64 + 255) / 256, 256, 0, stream>>>(Wv2s, Tb);
    aiaj_k<<<64, 64, 0, stream>>>(Wv2v, Wvl, Ai, Aj);
    edge_sorted_k<<<((N + CPW - 1) / CPW + 3) / 4, 256, 0, stream>>>(
        position, dis, PC, PR, vector, Tb, srow, sna, offB, outs, AGG2, B3, Bv, Wsum, N);
    finalize2_k<<<dim3((N + 255) / 256, 4), 256, 0, stream>>>(
        scalar, vector, Wsl, bsl, Wvl, Ai, Aj, AGG2, B3, Bv, Wsum, outs, outv, N);
}

// Round 4
// 487.822 us; speedup vs baseline: 3.4528x; 1.4950x over previous
//
#include <hip/hip_runtime.h>

// ---------------------------------------------------------------------------
// MolNet layer, round 4: all dense projections via bf16 MFMA GEMMs.
//   - node_pre:  PC/PR = X[40000x128] @ 6x(64x64 blocks)   (bf16 out)
//   - edge kernel: col-sorted, register accumulation, writes bf16 Xs/Xv
//   - finalize:  outs = silu(Xs@Wsl + wsn*bsl) + scalar
//                outv = Xv[120000x192] @ [Wvl_bot;Aj;Ai] + vec
//   Fragment layouts (16x16x32 bf16, gfx950):
//     A[m=lane&15][k=(lane>>4)*8+j]  B^T[n=lane&15][k=(lane>>4)*8+j]
//     C/D: col=lane&15, row=(lane>>4)*4+reg
// ---------------------------------------------------------------------------

typedef __attribute__((ext_vector_type(8))) short bf16x8;
typedef __attribute__((ext_vector_type(4))) float f32x4;
#define MFMA16(a, b, c) __builtin_amdgcn_mfma_f32_16x16x32_bf16(a, b, c, 0, 0, 0)

__device__ __forceinline__ float silu_f(float x) { return x / (1.0f + __expf(-x)); }
__device__ __forceinline__ float tanh_f(float x) { return 1.0f - 2.0f / (1.0f + __expf(2.0f * x)); }

__device__ __forceinline__ unsigned short f2bf(float x) {
    union { float f; unsigned u; } v; v.f = x;
    unsigned r = v.u + 0x7FFF + ((v.u >> 16) & 1);
    return (unsigned short)(r >> 16);
}
__device__ __forceinline__ float bf2f(unsigned short h) {
    union { unsigned u; float f; } v; v.u = ((unsigned)h) << 16; return v.f;
}

// ---------------- sort pipeline (unchanged) --------------------------------
__global__ __launch_bounds__(256) void deg_cnt_k(const int* __restrict__ ei,
                                                 const float* __restrict__ attr,
                                                 float* __restrict__ deg,
                                                 int* __restrict__ cnt, int E) {
    int e = blockIdx.x * 256 + threadIdx.x;
    if (e < E) {
        int col = ei[E + e];
        atomicAdd(&deg[col], attr[e]);
        atomicAdd(&cnt[col], 1);
    }
}

__global__ __launch_bounds__(256) void dis_k(const float* __restrict__ deg,
                                             float* __restrict__ dis, int N) {
    int n = blockIdx.x * 256 + threadIdx.x;
    if (n < N) {
        float d = deg[n];
        dis[n] = (d > 0.0f) ? rsqrtf(d) : 0.0f;
    }
}

__global__ __launch_bounds__(1024) void scan1_k(const int* __restrict__ cnt,
                                                int* __restrict__ blockSums, int N) {
    __shared__ int tmp[1024];
    int i = blockIdx.x * 1024 + threadIdx.x;
    tmp[threadIdx.x] = (i < N) ? cnt[i] : 0;
    __syncthreads();
    for (int s = 512; s > 0; s >>= 1) {
        if (threadIdx.x < s) tmp[threadIdx.x] += tmp[threadIdx.x + s];
        __syncthreads();
    }
    if (threadIdx.x == 0) blockSums[blockIdx.x] = tmp[0];
}

__global__ __launch_bounds__(64) void scan2_k(int* __restrict__ blockSums, int nb) {
    int t = threadIdx.x;
    int own = (t < nb) ? blockSums[t] : 0;
    int v = own;
    for (int s = 1; s < 64; s <<= 1) {
        int up = __shfl_up(v, s);
        if (t >= s) v += up;
    }
    if (t < nb) blockSums[t] = v - own;
}

__global__ __launch_bounds__(1024) void scan3_k(const int* __restrict__ cnt,
                                                const int* __restrict__ blockSums,
                                                int* __restrict__ offA,
                                                int* __restrict__ offB, int N) {
    __shared__ int tmp[1024];
    int i = blockIdx.x * 1024 + threadIdx.x;
    tmp[threadIdx.x] = (i < N) ? cnt[i] : 0;
    __syncthreads();
    for (int s = 1; s < 1024; s <<= 1) {
        int t = (threadIdx.x >= s) ? tmp[threadIdx.x - s] : 0;
        __syncthreads();
        tmp[threadIdx.x] += t;
        __syncthreads();
    }
    if (i < N) {
        int off = blockSums[blockIdx.x] + tmp[threadIdx.x];
        offA[i + 1] = off;
        offB[i + 1] = off;
    }
    if (blockIdx.x == 0 && threadIdx.x == 0) { offA[0] = 0; offB[0] = 0; }
}

__global__ __launch_bounds__(256) void scatter_k(const int* __restrict__ ei,
                                                 const float* __restrict__ attr,
                                                 const float* __restrict__ dis,
                                                 int* __restrict__ offA,
                                                 int* __restrict__ srow,
                                                 float* __restrict__ sna, int E) {
    int e = blockIdx.x * 256 + threadIdx.x;
    if (e < E) {
        int row = ei[e];
        int col = ei[E + e];
        int p = atomicAdd(&offA[col], 1);
        srow[p] = row;
        sna[p] = dis[row] * attr[e];
    }
}

// ---------------- small prep kernels ---------------------------------------
// X[n][0:64]=bf16(scalar[n]), X[n][64:128]=bf16(||vec[n]||); vb16 = bf16(vec)
__global__ __launch_bounds__(256) void xbuild_k(const float* __restrict__ scalar,
                                                const float* __restrict__ vec,
                                                unsigned short* __restrict__ X,
                                                unsigned short* __restrict__ vb, int N) {
    int idx = blockIdx.x * 256 + threadIdx.x;
    if (idx >= N * 64) return;
    int n = idx >> 6, c = idx & 63;
    float v0 = vec[(size_t)n * 192 + c];
    float v1 = vec[(size_t)n * 192 + 64 + c];
    float v2 = vec[(size_t)n * 192 + 128 + c];
    X[(size_t)n * 128 + c] = f2bf(scalar[(size_t)n * 64 + c]);
    X[(size_t)n * 128 + 64 + c] = f2bf(sqrtf(v0 * v0 + v1 * v1 + v2 * v2));
    vb[(size_t)n * 192 + c] = f2bf(v0);
    vb[(size_t)n * 192 + 64 + c] = f2bf(v1);
    vb[(size_t)n * 192 + 128 + c] = f2bf(v2);
}

// Transposed bf16 weights: BT6[y][n][k] = W_y[k][n] (6 64x64 blocks),
// BTs[n][k] = Wsl[k][n] (k<128), BTv[n][k] = Wvl[64+k][n] for k<64.
__global__ __launch_bounds__(256) void wpack_k(const float* __restrict__ Ws2s,
                                               const float* __restrict__ Ws2v,
                                               const float* __restrict__ Wv2s,
                                               const float* __restrict__ Wsl,
                                               const float* __restrict__ Wvl,
                                               unsigned short* __restrict__ BT6,
                                               unsigned short* __restrict__ BTs,
                                               unsigned short* __restrict__ BTv) {
    int idx = blockIdx.x * 256 + threadIdx.x;
    if (idx < 6 * 4096) {
        int y = idx >> 12, n = (idx >> 6) & 63, k = idx & 63;
        const float* W = (y < 2) ? Ws2s : (y < 4) ? Ws2v : Wv2s;
        int kk = (y & 1) ? (64 + k) : k;
        BT6[idx] = f2bf(W[kk * 64 + n]);
    } else if (idx < 6 * 4096 + 8192) {
        int j = idx - 6 * 4096;
        int n = j >> 7, k = j & 127;
        BTs[(size_t)n * 128 + k] = f2bf(Wsl[k * 64 + n]);
    } else if (idx < 6 * 4096 + 8192 + 4096) {
        int j = idx - 6 * 4096 - 8192;
        int n = j >> 6, k = j & 63;
        BTv[(size_t)n * 192 + k] = f2bf(Wvl[(64 + k) * 64 + n]);
    }
}

// Aj = Wv2v_bot@Wvl_top, Ai = Wv2v_top@Wvl_top -> BTv[n][64+k], BTv[n][128+k]
__global__ void aiaj_k(const float* __restrict__ Wv2v, const float* __restrict__ Wvl,
                       unsigned short* __restrict__ BTv) {
    int k = blockIdx.x, c = threadIdx.x;
    float ai = 0.0f, aj = 0.0f;
    for (int m = 0; m < 64; ++m) {
        float w = Wvl[m * 64 + c];
        ai += Wv2v[k * 64 + m] * w;
        aj += Wv2v[(64 + k) * 64 + m] * w;
    }
    BTv[(size_t)c * 192 + 64 + k] = f2bf(aj);
    BTv[(size_t)c * 192 + 128 + k] = f2bf(ai);
}

__global__ __launch_bounds__(256) void rbf_table_k(const float* __restrict__ Wv2s,
                                                   float* __restrict__ T) {
    int idx = blockIdx.x * 256 + threadIdx.x;
    if (idx >= 1025 * 64) return;
    int s = idx >> 6, c = idx & 63;
    float d = (float)s * (6.0f / 1024.0f);
    float acc = 0.0f;
    for (int l = 0; l < 50; ++l) {
        float dl = d - 0.10204081632653061f * (float)l;
        acc += __expf(-48.02f * dl * dl) * Wv2s[(128 + l) * 64 + c];
    }
    T[idx] = acc;
}

// ---------------- node precompute GEMM -------------------------------------
// grid (mtiles/4, 6), block 256. wave = one 16-row M-tile, N=64, K=64.
__global__ __launch_bounds__(256) void node_gemm_k(
    const unsigned short* __restrict__ X,    // [N][128]
    const unsigned short* __restrict__ BT6,  // [6][64][64]
    const float* __restrict__ bs2s, const float* __restrict__ bs2v,
    const float* __restrict__ bv2s,
    unsigned short* __restrict__ PC, unsigned short* __restrict__ PR, int N) {
    const int y = blockIdx.y;
    const int lane = threadIdx.x & 63;
    const int mtile = blockIdx.x * 4 + (threadIdx.x >> 6);
    const int r0 = mtile * 16;
    if (r0 >= N) return;
    const int quad = lane >> 4;
    const int xoff = (y < 4) ? 0 : 64;
    const int arow = min(r0 + (lane & 15), N - 1);
    const unsigned short* aptr = X + (size_t)arow * 128 + xoff + quad * 8;
    bf16x8 a0 = *(const bf16x8*)aptr;
    bf16x8 a1 = *(const bf16x8*)(aptr + 32);
    const unsigned short* bptr = BT6 + (size_t)y * 4096 + (size_t)(lane & 15) * 64 + quad * 8;
    f32x4 acc[4];
#pragma unroll
    for (int nt = 0; nt < 4; ++nt) {
        acc[nt] = (f32x4){0.f, 0.f, 0.f, 0.f};
        bf16x8 b0 = *(const bf16x8*)(bptr + nt * 1024);
        bf16x8 b1 = *(const bf16x8*)(bptr + nt * 1024 + 32);
        acc[nt] = MFMA16(a0, b0, acc[nt]);
        acc[nt] = MFMA16(a1, b1, acc[nt]);
    }
    const float* bias = (y == 0) ? bs2s : (y == 2) ? bs2v : (y == 4) ? bv2s : nullptr;
    unsigned short* dst = ((y & 1) ? PR : PC);
    const int seg = (y >> 1) * 64;
#pragma unroll
    for (int nt = 0; nt < 4; ++nt) {
        int col = nt * 16 + (lane & 15);
        float bv = bias ? bias[col] : 0.0f;
#pragma unroll
        for (int i = 0; i < 4; ++i) {
            int row = r0 + quad * 4 + i;
            if (row < N) dst[(size_t)row * 192 + seg + col] = f2bf(acc[nt][i] + bv);
        }
    }
}

// ---------------- edge kernel (bf16 gathers, bf16 Xs/Xv outputs) -----------
#define CPW 4
__global__ __launch_bounds__(256) void edge_sorted_k(
    const float* __restrict__ pos, const float* __restrict__ dis,
    const unsigned short* __restrict__ PC, const unsigned short* __restrict__ PR,
    const unsigned short* __restrict__ vb, const float* __restrict__ T,
    const int* __restrict__ srow, const float* __restrict__ sna,
    const int* __restrict__ offB,
    unsigned short* __restrict__ Xs, unsigned short* __restrict__ Xv,
    float* __restrict__ Wsum, int N) {
    const int lane = threadIdx.x & 63;
    const int wave = (blockIdx.x * 256 + threadIdx.x) >> 6;
    const int c0 = wave * CPW;
    const int cend = min(c0 + CPW, N);
    for (int col = c0; col < cend; ++col) {
        const int e0 = offB[col], e1 = offB[col + 1];
        const float dcol = dis[col];
        const float px = pos[col * 3], py = pos[col * 3 + 1], pz = pos[col * 3 + 2];
        const size_t cb = (size_t)col * 192;
        const float pc0 = bf2f(PC[cb + lane]);
        const float pc1 = bf2f(PC[cb + 64 + lane]);
        const float pc2 = bf2f(PC[cb + 128 + lane]);
        float a1 = 0, a2 = 0, ws = 0;
        float b30 = 0, b31 = 0, b32 = 0, bv0 = 0, bv1 = 0, bv2 = 0;
        for (int e = e0; e < e1; ++e) {
            const int row = srow[e];
            const float nrm = dcol * sna[e];
            const size_t rb = (size_t)row * 192;
            const float r0 = px - pos[row * 3 + 0];
            const float r1 = py - pos[row * 3 + 1];
            const float r2 = pz - pos[row * 3 + 2];
            const float dist = sqrtf(r0 * r0 + r1 * r1 + r2 * r2);
            float t = fminf(dist * (1024.0f / 6.0f), 1023.0f);
            int s0 = (int)t;
            float f = t - (float)s0;
            float T0 = T[s0 * 64 + lane], T1 = T[s0 * 64 + 64 + lane];
            float rbfw = T0 + f * (T1 - T0);
            float ss = silu_f(pc0 + bf2f(PR[rb + lane]));
            float tt = tanh_f(pc1 + bf2f(PR[rb + 64 + lane]));
            float vs = silu_f(pc2 + bf2f(PR[rb + 128 + lane]) + rbfw);
            ws += nrm;
            a1 += nrm * ss;
            a2 += nrm * vs;
            float nt = nrm * tt;
            b30 += nt * r0; b31 += nt * r1; b32 += nt * r2;
            bv0 += nrm * bf2f(vb[rb + lane]);
            bv1 += nrm * bf2f(vb[rb + 64 + lane]);
            bv2 += nrm * bf2f(vb[rb + 128 + lane]);
        }
        Xs[(size_t)col * 128 + lane] = f2bf(a1);
        Xs[(size_t)col * 128 + 64 + lane] = f2bf(a2);
        const size_t xb = (size_t)col * 576;
        Xv[xb + lane]       = f2bf(b30);
        Xv[xb + 64 + lane]  = f2bf(bv0);
        Xv[xb + 128 + lane] = f2bf(ws * bf2f(vb[cb + lane]));
        Xv[xb + 192 + lane] = f2bf(b31);
        Xv[xb + 256 + lane] = f2bf(bv1);
        Xv[xb + 320 + lane] = f2bf(ws * bf2f(vb[cb + 64 + lane]));
        Xv[xb + 384 + lane] = f2bf(b32);
        Xv[xb + 448 + lane] = f2bf(bv2);
        Xv[xb + 512 + lane] = f2bf(ws * bf2f(vb[cb + 128 + lane]));
        if (lane == 0) Wsum[col] = ws;
    }
}

// ---------------- finalize GEMMs -------------------------------------------
// scalar path: outs = silu(Xs[40000x128]@Wsl + wsn*bsl) + scalar
__global__ __launch_bounds__(256) void gemm_s_k(
    const unsigned short* __restrict__ Xs, const unsigned short* __restrict__ BTs,
    const float* __restrict__ bsl, const float* __restrict__ Wsum,
    const float* __restrict__ scalar, float* __restrict__ outs, int N) {
    const int lane = threadIdx.x & 63;
    const int mtile = blockIdx.x * 4 + (threadIdx.x >> 6);
    const int r0 = mtile * 16;
    if (r0 >= N) return;
    const int quad = lane >> 4;
    const int arow = min(r0 + (lane & 15), N - 1);
    const unsigned short* aptr = Xs + (size_t)arow * 128 + quad * 8;
    bf16x8 a[4];
#pragma unroll
    for (int s = 0; s < 4; ++s) a[s] = *(const bf16x8*)(aptr + s * 32);
    const unsigned short* bptr = BTs + (size_t)(lane & 15) * 128 + quad * 8;
    f32x4 acc[4];
#pragma unroll
    for (int nt = 0; nt < 4; ++nt) {
        acc[nt] = (f32x4){0.f, 0.f, 0.f, 0.f};
#pragma unroll
        for (int s = 0; s < 4; ++s) {
            bf16x8 b = *(const bf16x8*)(bptr + (size_t)nt * 16 * 128 + s * 32);
            acc[nt] = MFMA16(a[s], b, acc[nt]);
        }
    }
#pragma unroll
    for (int nt = 0; nt < 4; ++nt) {
        int col = nt * 16 + (lane & 15);
        float bc = bsl[col];
#pragma unroll
        for (int i = 0; i < 4; ++i) {
            int row = r0 + quad * 4 + i;
            if (row < N) {
                float wsn = Wsum[row];
                outs[(size_t)row * 64 + col] =
                    silu_f(acc[nt][i] + wsn * bc) + scalar[(size_t)row * 64 + col];
            }
        }
    }
}

// vector path: outv = Xv[120000x192]@[Wvl_bot;Aj;Ai] + vec   (M = 3N rows)
__global__ __launch_bounds__(256) void gemm_v_k(
    const unsigned short* __restrict__ Xv, const unsigned short* __restrict__ BTv,
    const float* __restrict__ vec, float* __restrict__ outv, int M) {
    const int lane = threadIdx.x & 63;
    const int mtile = blockIdx.x * 4 + (threadIdx.x >> 6);
    const int r0 = mtile * 16;
    if (r0 >= M) return;
    const int quad = lane >> 4;
    const int arow = min(r0 + (lane & 15), M - 1);
    const unsigned short* aptr = Xv + (size_t)arow * 192 + quad * 8;
    bf16x8 a[6];
#pragma unroll
    for (int s = 0; s < 6; ++s) a[s] = *(const bf16x8*)(aptr + s * 32);
    const unsigned short* bptr = BTv + (size_t)(lane & 15) * 192 + quad * 8;
    f32x4 acc[4];
#pragma unroll
    for (int nt = 0; nt < 4; ++nt) {
        acc[nt] = (f32x4){0.f, 0.f, 0.f, 0.f};
#pragma unroll
        for (int s = 0; s < 6; ++s) {
            bf16x8 b = *(const bf16x8*)(bptr + (size_t)nt * 16 * 192 + s * 32);
            acc[nt] = MFMA16(a[s], b, acc[nt]);
        }
    }
#pragma unroll
    for (int nt = 0; nt < 4; ++nt) {
        int col = nt * 16 + (lane & 15);
#pragma unroll
        for (int i = 0; i < 4; ++i) {
            int row = r0 + quad * 4 + i;
            if (row < M)
                outv[(size_t)row * 64 + col] = acc[nt][i] + vec[(size_t)row * 64 + col];
        }
    }
}

extern "C" void kernel_launch(void* const* d_in, const int* in_sizes, int n_in,
                              void* d_out, int out_size, void* d_ws, size_t ws_size,
                              hipStream_t stream) {
    const float* scalar     = (const float*)d_in[0];
    const float* vector     = (const float*)d_in[1];
    const float* position   = (const float*)d_in[2];
    const int*   edge_index = (const int*)d_in[3];
    const float* edge_attr  = (const float*)d_in[4];
    const float* Ws2s       = (const float*)d_in[5];
    const float* bs2s       = (const float*)d_in[6];
    const float* Wv2s       = (const float*)d_in[7];
    const float* bv2s       = (const float*)d_in[8];
    const float* Wsl        = (const float*)d_in[9];
    const float* bsl        = (const float*)d_in[10];
    const float* Ws2v       = (const float*)d_in[11];
    const float* bs2v       = (const float*)d_in[12];
    const float* Wv2v       = (const float*)d_in[13];
    const float* Wvl        = (const float*)d_in[14];

    const int N = in_sizes[0] / 64;
    const int E = in_sizes[3] / 2;
    const size_t sN = (size_t)N;
    const int nb = (N + 1023) / 1024;

    float* W = (float*)d_ws;
    // layout (float slots), with lifetime overlays:
    float*          dis  = W;                                  // N
    unsigned short* X    = (unsigned short*)(W + sN);          // 128N bf16 (64N fl)
    unsigned short* Xs   = X;                                  // overlay (post node_gemm)
    unsigned short* vb16 = (unsigned short*)(W + 65 * sN);     // 192N bf16 (96N fl)
    unsigned short* PC   = (unsigned short*)(W + 161 * sN);    // 192N bf16
    unsigned short* PR   = (unsigned short*)(W + 257 * sN);    // 192N bf16
    unsigned short* Xv   = (unsigned short*)(W + 353 * sN);    // 576N bf16 (288N fl)
    //   overlays inside Xv region (dead before edge kernel writes Xv):
    float* deg       = W + 353 * sN;                           // N
    int*   cnt       = (int*)(W + 354 * sN);                   // N
    int*   offA      = (int*)(W + 355 * sN);                   // N+1
    int*   blockSums = (int*)(W + 357 * sN);                   // nb
    unsigned short* BT6 = (unsigned short*)(W + 358 * sN);     // 24576 bf16
    float* Wsum = W + 641 * sN;                                // N
    int*   offB = (int*)(W + 642 * sN);                        // N+1
    unsigned short* BTs = (unsigned short*)(W + 644 * sN);     // 8192 bf16 (4096 fl)
    unsigned short* BTv = (unsigned short*)(W + 644 * sN + 4096);  // 12288 bf16 (6144 fl)
    float* Tb   = W + 644 * sN + 4096 + 6144;                  // 65600 fl
    int*   srow = (int*)(W + 646 * sN);                        // 16N
    float* sna  = W + 662 * sN;                                // 16N  (ends 678N)

    float* outs = (float*)d_out;                               // 64N
    float* outv = outs + 64 * sN;                              // 192N

    hipMemsetAsync(deg, 0, sizeof(float) * sN, stream);
    hipMemsetAsync(cnt, 0, sizeof(int) * sN, stream);

    deg_cnt_k<<<(E + 255) / 256, 256, 0, stream>>>(edge_index, edge_attr, deg, cnt, E);
    dis_k<<<(N + 255) / 256, 256, 0, stream>>>(deg, dis, N);
    scan1_k<<<nb, 1024, 0, stream>>>(cnt, blockSums, N);
    scan2_k<<<1, 64, 0, stream>>>(blockSums, nb);
    scan3_k<<<nb, 1024, 0, stream>>>(cnt, blockSums, offA, offB, N);
    scatter_k<<<(E + 255) / 256, 256, 0, stream>>>(edge_index, edge_attr, dis, offA, srow, sna, E);

    xbuild_k<<<(N * 64 + 255) / 256, 256, 0, stream>>>(scalar, vector, X, vb16, N);
    wpack_k<<<(6 * 4096 + 8192 + 4096 + 255) / 256, 256, 0, stream>>>(
        Ws2s, Ws2v, Wv2s, Wsl, Wvl, BT6, BTs, BTv);
    aiaj_k<<<64, 64, 0, stream>>>(Wv2v, Wvl, BTv);
    rbf_table_k<<<(1025 * 64 + 255) / 256, 256, 0, stream>>>(Wv2s, Tb);

    const int mtilesN = (N + 15) / 16;
    node_gemm_k<<<dim3((mtilesN + 3) / 4, 6), 256, 0, stream>>>(
        X, BT6, bs2s, bs2v, bv2s, PC, PR, N);

    edge_sorted_k<<<((N + CPW - 1) / CPW + 3) / 4, 256, 0, stream>>>(
        position, dis, PC, PR, vb16, Tb, srow, sna, offB, Xs, Xv, Wsum, N);

    gemm_s_k<<<(mtilesN + 3) / 4, 256, 0, stream>>>(Xs, BTs, bsl, Wsum, scalar, outs, N);
    const int M = 3 * N;
    gemm_v_k<<<((M + 15) / 16 + 3) / 4, 256, 0, stream>>>(Xv, BTv, vector, outv, M);
}

// Round 5
// 439.950 us; speedup vs baseline: 3.8285x; 1.1088x over previous
//
#include <hip/hip_runtime.h>

// ---------------------------------------------------------------------------
// MolNet layer, round 5:
//   - edge kernel: wave-uniform values forced into SGPRs (readfirstlane),
//     single combined row-gather array R[row][384] = [PR0|PR1|PR2|vb0|vb1|vb2],
//     rcp-based silu/tanh, RBF via LUT with scalar base.
//   - sort pipeline: deg+cnt packed per cache line, srow+sna packed int2,
//     dis folded into scan3. Weight prep fused into one kernel.
//   - dense projections via bf16 MFMA GEMMs (node_pre, finalize s/v).
// ---------------------------------------------------------------------------

typedef __attribute__((ext_vector_type(8))) short bf16x8;
typedef __attribute__((ext_vector_type(4))) float f32x4;
#define MFMA16(a, b, c) __builtin_amdgcn_mfma_f32_16x16x32_bf16(a, b, c, 0, 0, 0)

__device__ __forceinline__ unsigned short f2bf(float x) {
    union { float f; unsigned u; } v; v.f = x;
    unsigned r = v.u + 0x7FFF + ((v.u >> 16) & 1);
    return (unsigned short)(r >> 16);
}
__device__ __forceinline__ float bf2f(unsigned short h) {
    union { unsigned u; float f; } v; v.u = ((unsigned)h) << 16; return v.f;
}
__device__ __forceinline__ float silu_f(float x) {
    return x * __builtin_amdgcn_rcpf(1.0f + __expf(-x));
}
__device__ __forceinline__ float tanh_f(float x) {
    return 1.0f - 2.0f * __builtin_amdgcn_rcpf(1.0f + __expf(2.0f * x));
}
__device__ __forceinline__ int rfl(int x) { return __builtin_amdgcn_readfirstlane(x); }

// ---------------- sort pipeline --------------------------------------------
// dc[n] = {deg(float), cnt(int)} packed in one 8B slot (one cache line / node pair)
__global__ __launch_bounds__(256) void deg_cnt_k(const int* __restrict__ ei,
                                                 const float* __restrict__ attr,
                                                 float* __restrict__ dc, int E) {
    int e = blockIdx.x * 256 + threadIdx.x;
    if (e < E) {
        int col = ei[E + e];
        atomicAdd(&dc[2 * col], attr[e]);
        atomicAdd((int*)dc + 2 * col + 1, 1);
    }
}

__global__ __launch_bounds__(1024) void scan1_k(const float* __restrict__ dc,
                                                int* __restrict__ blockSums, int N) {
    __shared__ int tmp[1024];
    int i = blockIdx.x * 1024 + threadIdx.x;
    tmp[threadIdx.x] = (i < N) ? ((const int*)dc)[2 * i + 1] : 0;
    __syncthreads();
    for (int s = 512; s > 0; s >>= 1) {
        if (threadIdx.x < s) tmp[threadIdx.x] += tmp[threadIdx.x + s];
        __syncthreads();
    }
    if (threadIdx.x == 0) blockSums[blockIdx.x] = tmp[0];
}

__global__ __launch_bounds__(64) void scan2_k(int* __restrict__ blockSums, int nb) {
    int t = threadIdx.x;
    int own = (t < nb) ? blockSums[t] : 0;
    int v = own;
    for (int s = 1; s < 64; s <<= 1) {
        int up = __shfl_up(v, s);
        if (t >= s) v += up;
    }
    if (t < nb) blockSums[t] = v - own;
}

// also computes dis[] from packed deg
__global__ __launch_bounds__(1024) void scan3_k(const float* __restrict__ dc,
                                                const int* __restrict__ blockSums,
                                                int* __restrict__ offA,
                                                int* __restrict__ offB,
                                                float* __restrict__ dis, int N) {
    __shared__ int tmp[1024];
    int i = blockIdx.x * 1024 + threadIdx.x;
    tmp[threadIdx.x] = (i < N) ? ((const int*)dc)[2 * i + 1] : 0;
    __syncthreads();
    for (int s = 1; s < 1024; s <<= 1) {
        int t = (threadIdx.x >= s) ? tmp[threadIdx.x - s] : 0;
        __syncthreads();
        tmp[threadIdx.x] += t;
        __syncthreads();
    }
    if (i < N) {
        int off = blockSums[blockIdx.x] + tmp[threadIdx.x];
        offA[i + 1] = off;
        offB[i + 1] = off;
        float d = dc[2 * i];
        dis[i] = (d > 0.0f) ? rsqrtf(d) : 0.0f;
    }
    if (blockIdx.x == 0 && threadIdx.x == 0) { offA[0] = 0; offB[0] = 0; }
}

// SE[p] = {row, bits(dis[row]*attr)} single 8B write
__global__ __launch_bounds__(256) void scatter_k(const int* __restrict__ ei,
                                                 const float* __restrict__ attr,
                                                 const float* __restrict__ dis,
                                                 int* __restrict__ offA,
                                                 int2* __restrict__ SE, int E) {
    int e = blockIdx.x * 256 + threadIdx.x;
    if (e < E) {
        int row = ei[e];
        int col = ei[E + e];
        int p = atomicAdd(&offA[col], 1);
        SE[p] = make_int2(row, __float_as_int(dis[row] * attr[e]));
    }
}

// ---------------- fused prep: X, R(vb), weights, Ai/Aj, RBF table ----------
// X[n][0:64]=bf16(scalar), X[n][64:128]=bf16(||vec||); R[n][192..384]=bf16(vec)
__global__ __launch_bounds__(256) void xbuild_k(const float* __restrict__ scalar,
                                                const float* __restrict__ vec,
                                                unsigned short* __restrict__ X,
                                                unsigned short* __restrict__ R, int N) {
    int idx = blockIdx.x * 256 + threadIdx.x;
    if (idx >= N * 64) return;
    int n = idx >> 6, c = idx & 63;
    float v0 = vec[(size_t)n * 192 + c];
    float v1 = vec[(size_t)n * 192 + 64 + c];
    float v2 = vec[(size_t)n * 192 + 128 + c];
    X[(size_t)n * 128 + c] = f2bf(scalar[(size_t)n * 64 + c]);
    X[(size_t)n * 128 + 64 + c] = f2bf(sqrtf(v0 * v0 + v1 * v1 + v2 * v2));
    unsigned short* Rr = R + (size_t)n * 384 + 192;
    Rr[c] = f2bf(v0); Rr[64 + c] = f2bf(v1); Rr[128 + c] = f2bf(v2);
}

// idx ranges: BT6 (24576) | BTs (8192) | BTv k<64 (4096) | Aj/Ai (8192) | rbf T (65600)
__global__ __launch_bounds__(256) void prep_k(const float* __restrict__ Ws2s,
                                              const float* __restrict__ Ws2v,
                                              const float* __restrict__ Wv2s,
                                              const float* __restrict__ Wsl,
                                              const float* __restrict__ Wvl,
                                              const float* __restrict__ Wv2v,
                                              unsigned short* __restrict__ BT6,
                                              unsigned short* __restrict__ BTs,
                                              unsigned short* __restrict__ BTv,
                                              float* __restrict__ T) {
    int idx = blockIdx.x * 256 + threadIdx.x;
    if (idx < 24576) {
        int y = idx >> 12, n = (idx >> 6) & 63, k = idx & 63;
        const float* W = (y < 2) ? Ws2s : (y < 4) ? Ws2v : Wv2s;
        int kk = (y & 1) ? (64 + k) : k;
        BT6[idx] = f2bf(W[kk * 64 + n]);
    } else if (idx < 24576 + 8192) {
        int j = idx - 24576;
        int n = j >> 7, k = j & 127;
        BTs[(size_t)n * 128 + k] = f2bf(Wsl[k * 64 + n]);
    } else if (idx < 24576 + 8192 + 4096) {
        int j = idx - 24576 - 8192;
        int n = j >> 6, k = j & 63;
        BTv[(size_t)n * 192 + k] = f2bf(Wvl[(64 + k) * 64 + n]);
    } else if (idx < 24576 + 8192 + 4096 + 8192) {
        int j = idx - 24576 - 8192 - 4096;
        int half = j >> 12;            // 0: Aj (row side), 1: Ai (col side)
        int k = (j >> 6) & 63, c = j & 63;
        const float* Wr = Wv2v + (half ? 0 : 64 * 64) + k * 64;
        float acc = 0.0f;
        for (int m = 0; m < 64; ++m) acc += Wr[m] * Wvl[m * 64 + c];
        BTv[(size_t)c * 192 + (half ? 128 : 64) + k] = f2bf(acc);
    } else {
        int j = idx - 24576 - 8192 - 4096 - 8192;
        if (j >= 1025 * 64) return;
        int s = j >> 6, c = j & 63;
        float d = (float)s * (6.0f / 1024.0f);
        float acc = 0.0f;
        for (int l = 0; l < 50; ++l) {
            float dl = d - 0.10204081632653061f * (float)l;
            acc += __expf(-48.02f * dl * dl) * Wv2s[(128 + l) * 64 + c];
        }
        T[j] = acc;
    }
}

// ---------------- node precompute GEMM -------------------------------------
// PC (even y) -> PC[col][192]; PR (odd y) -> R[row][384] segments 0..2
__global__ __launch_bounds__(256) void node_gemm_k(
    const unsigned short* __restrict__ X, const unsigned short* __restrict__ BT6,
    const float* __restrict__ bs2s, const float* __restrict__ bs2v,
    const float* __restrict__ bv2s,
    unsigned short* __restrict__ PC, unsigned short* __restrict__ R, int N) {
    const int y = blockIdx.y;
    const int lane = threadIdx.x & 63;
    const int mtile = blockIdx.x * 4 + (threadIdx.x >> 6);
    const int r0 = mtile * 16;
    if (r0 >= N) return;
    const int quad = lane >> 4;
    const int xoff = (y < 4) ? 0 : 64;
    const int arow = min(r0 + (lane & 15), N - 1);
    const unsigned short* aptr = X + (size_t)arow * 128 + xoff + quad * 8;
    bf16x8 a0 = *(const bf16x8*)aptr;
    bf16x8 a1 = *(const bf16x8*)(aptr + 32);
    const unsigned short* bptr = BT6 + (size_t)y * 4096 + (size_t)(lane & 15) * 64 + quad * 8;
    f32x4 acc[4];
#pragma unroll
    for (int nt = 0; nt < 4; ++nt) {
        acc[nt] = (f32x4){0.f, 0.f, 0.f, 0.f};
        bf16x8 b0 = *(const bf16x8*)(bptr + nt * 1024);
        bf16x8 b1 = *(const bf16x8*)(bptr + nt * 1024 + 32);
        acc[nt] = MFMA16(a0, b0, acc[nt]);
        acc[nt] = MFMA16(a1, b1, acc[nt]);
    }
    const float* bias = (y == 0) ? bs2s : (y == 2) ? bs2v : (y == 4) ? bv2s : nullptr;
    const bool toR = (y & 1);
    unsigned short* dst = toR ? R : PC;
    const size_t stride = toR ? 384 : 192;
    const int seg = (y >> 1) * 64;
#pragma unroll
    for (int nt = 0; nt < 4; ++nt) {
        int col = nt * 16 + (lane & 15);
        float bv = bias ? bias[col] : 0.0f;
#pragma unroll
        for (int i = 0; i < 4; ++i) {
            int row = r0 + quad * 4 + i;
            if (row < N) dst[(size_t)row * stride + seg + col] = f2bf(acc[nt][i] + bv);
        }
    }
}

// ---------------- edge kernel ----------------------------------------------
#define CPW 4
__global__ __launch_bounds__(256) void edge_sorted_k(
    const float* __restrict__ pos, const float* __restrict__ dis,
    const unsigned short* __restrict__ PC, const unsigned short* __restrict__ R,
    const float* __restrict__ T, const int2* __restrict__ SE,
    const int* __restrict__ offB,
    unsigned short* __restrict__ Xs, unsigned short* __restrict__ Xv,
    float* __restrict__ Wsum, int N) {
    const int lane = threadIdx.x & 63;
    const int wave = rfl((blockIdx.x * 256 + threadIdx.x) >> 6);
    const int c0 = wave * CPW;
    const int cend = min(c0 + CPW, N);
    for (int col = c0; col < cend; ++col) {
        const int e0 = rfl(offB[col]);
        const int e1 = rfl(offB[col + 1]);
        const float dcol = dis[col];
        const float px = pos[col * 3], py = pos[col * 3 + 1], pz = pos[col * 3 + 2];
        const unsigned short* Rc = R + (size_t)col * 384;
        const float pc0 = bf2f(PC[(size_t)col * 192 + lane]);
        const float pc1 = bf2f(PC[(size_t)col * 192 + 64 + lane]);
        const float pc2 = bf2f(PC[(size_t)col * 192 + 128 + lane]);
        const float wc0 = bf2f(Rc[192 + lane]);
        const float wc1 = bf2f(Rc[256 + lane]);
        const float wc2 = bf2f(Rc[320 + lane]);
        float a1 = 0, a2 = 0, ws = 0;
        float b30 = 0, b31 = 0, b32 = 0, bv0 = 0, bv1 = 0, bv2 = 0;
        for (int e = e0; e < e1; ++e) {
            const int2 se = SE[e];
            const int row = rfl(se.x);
            const float na = __int_as_float(rfl(se.y));
            const float nrm = dcol * na;
            const unsigned short* Rr = R + (size_t)row * 384;
            const float r0 = px - pos[row * 3 + 0];
            const float r1 = py - pos[row * 3 + 1];
            const float r2 = pz - pos[row * 3 + 2];
            const float dist = sqrtf(r0 * r0 + r1 * r1 + r2 * r2);
            float t = fminf(dist * (1024.0f / 6.0f), 1023.0f);
            int si = (int)t;
            float fr = t - (float)si;
            const float* Tp = T + (rfl(si) << 6);
            float T0 = Tp[lane], T1 = Tp[64 + lane];
            float rbfw = T0 + fr * (T1 - T0);
            float ss = silu_f(pc0 + bf2f(Rr[lane]));
            float tt = tanh_f(pc1 + bf2f(Rr[64 + lane]));
            float vs = silu_f(pc2 + bf2f(Rr[128 + lane]) + rbfw);
            ws += nrm;
            a1 += nrm * ss;
            a2 += nrm * vs;
            float nt = nrm * tt;
            b30 += nt * r0; b31 += nt * r1; b32 += nt * r2;
            bv0 += nrm * bf2f(Rr[192 + lane]);
            bv1 += nrm * bf2f(Rr[256 + lane]);
            bv2 += nrm * bf2f(Rr[320 + lane]);
        }
        Xs[(size_t)col * 128 + lane] = f2bf(a1);
        Xs[(size_t)col * 128 + 64 + lane] = f2bf(a2);
        const size_t xb = (size_t)col * 576;
        Xv[xb + lane]       = f2bf(b30);
        Xv[xb + 64 + lane]  = f2bf(bv0);
        Xv[xb + 128 + lane] = f2bf(ws * wc0);
        Xv[xb + 192 + lane] = f2bf(b31);
        Xv[xb + 256 + lane] = f2bf(bv1);
        Xv[xb + 320 + lane] = f2bf(ws * wc1);
        Xv[xb + 384 + lane] = f2bf(b32);
        Xv[xb + 448 + lane] = f2bf(bv2);
        Xv[xb + 512 + lane] = f2bf(ws * wc2);
        if (lane == 0) Wsum[col] = ws;
    }
}

// ---------------- finalize GEMMs -------------------------------------------
__global__ __launch_bounds__(256) void gemm_s_k(
    const unsigned short* __restrict__ Xs, const unsigned short* __restrict__ BTs,
    const float* __restrict__ bsl, const float* __restrict__ Wsum,
    const float* __restrict__ scalar, float* __restrict__ outs, int N) {
    const int lane = threadIdx.x & 63;
    const int mtile = blockIdx.x * 4 + (threadIdx.x >> 6);
    const int r0 = mtile * 16;
    if (r0 >= N) return;
    const int quad = lane >> 4;
    const int arow = min(r0 + (lane & 15), N - 1);
    const unsigned short* aptr = Xs + (size_t)arow * 128 + quad * 8;
    bf16x8 a[4];
#pragma unroll
    for (int s = 0; s < 4; ++s) a[s] = *(const bf16x8*)(aptr + s * 32);
    const unsigned short* bptr = BTs + (size_t)(lane & 15) * 128 + quad * 8;
    f32x4 acc[4];
#pragma unroll
    for (int nt = 0; nt < 4; ++nt) {
        acc[nt] = (f32x4){0.f, 0.f, 0.f, 0.f};
#pragma unroll
        for (int s = 0; s < 4; ++s) {
            bf16x8 b = *(const bf16x8*)(bptr + (size_t)nt * 16 * 128 + s * 32);
            acc[nt] = MFMA16(a[s], b, acc[nt]);
        }
    }
#pragma unroll
    for (int nt = 0; nt < 4; ++nt) {
        int col = nt * 16 + (lane & 15);
        float bc = bsl[col];
#pragma unroll
        for (int i = 0; i < 4; ++i) {
            int row = r0 + quad * 4 + i;
            if (row < N) {
                float wsn = Wsum[row];
                outs[(size_t)row * 64 + col] =
                    silu_f(acc[nt][i] + wsn * bc) + scalar[(size_t)row * 64 + col];
            }
        }
    }
}

__global__ __launch_bounds__(256) void gemm_v_k(
    const unsigned short* __restrict__ Xv, const unsigned short* __restrict__ BTv,
    const float* __restrict__ vec, float* __restrict__ outv, int M) {
    const int lane = threadIdx.x & 63;
    const int mtile = blockIdx.x * 4 + (threadIdx.x >> 6);
    const int r0 = mtile * 16;
    if (r0 >= M) return;
    const int quad = lane >> 4;
    const int arow = min(r0 + (lane & 15), M - 1);
    const unsigned short* aptr = Xv + (size_t)arow * 192 + quad * 8;
    bf16x8 a[6];
#pragma unroll
    for (int s = 0; s < 6; ++s) a[s] = *(const bf16x8*)(aptr + s * 32);
    const unsigned short* bptr = BTv + (size_t)(lane & 15) * 192 + quad * 8;
    f32x4 acc[4];
#pragma unroll
    for (int nt = 0; nt < 4; ++nt) {
        acc[nt] = (f32x4){0.f, 0.f, 0.f, 0.f};
#pragma unroll
        for (int s = 0; s < 6; ++s) {
            bf16x8 b = *(const bf16x8*)(bptr + (size_t)nt * 16 * 192 + s * 32);
            acc[nt] = MFMA16(a[s], b, acc[nt]);
        }
    }
#pragma unroll
    for (int nt = 0; nt < 4; ++nt) {
        int col = nt * 16 + (lane & 15);
#pragma unroll
        for (int i = 0; i < 4; ++i) {
            int row = r0 + quad * 4 + i;
            if (row < M)
                outv[(size_t)row * 64 + col] = acc[nt][i] + vec[(size_t)row * 64 + col];
        }
    }
}

extern "C" void kernel_launch(void* const* d_in, const int* in_sizes, int n_in,
                              void* d_out, int out_size, void* d_ws, size_t ws_size,
                              hipStream_t stream) {
    const float* scalar     = (const float*)d_in[0];
    const float* vector     = (const float*)d_in[1];
    const float* position   = (const float*)d_in[2];
    const int*   edge_index = (const int*)d_in[3];
    const float* edge_attr  = (const float*)d_in[4];
    const float* Ws2s       = (const float*)d_in[5];
    const float* bs2s       = (const float*)d_in[6];
    const float* Wv2s       = (const float*)d_in[7];
    const float* bv2s       = (const float*)d_in[8];
    const float* Wsl        = (const float*)d_in[9];
    const float* bsl        = (const float*)d_in[10];
    const float* Ws2v       = (const float*)d_in[11];
    const float* bs2v       = (const float*)d_in[12];
    const float* Wv2v       = (const float*)d_in[13];
    const float* Wvl        = (const float*)d_in[14];

    const int N = in_sizes[0] / 64;
    const int E = in_sizes[3] / 2;
    const size_t sN = (size_t)N;
    const int nb = (N + 1023) / 1024;

    float* W = (float*)d_ws;
    // float-slot layout with lifetime overlays:
    float*          dis  = W;                               // N
    unsigned short* X    = (unsigned short*)(W + sN);       // 128N bf16 (64N fl)
    unsigned short* Xs   = X;                               // overlay post node_gemm
    unsigned short* R    = (unsigned short*)(W + 65 * sN);  // 384N bf16 (192N fl)
    unsigned short* PC   = (unsigned short*)(W + 257 * sN); // 192N bf16 (96N fl)
    unsigned short* Xv   = (unsigned short*)(W + 353 * sN); // 576N bf16 (288N fl)
    //   overlays inside Xv region (dead before edge kernel writes Xv):
    float* dc        = W + 353 * sN;                        // 2N (deg,cnt packed)
    int*   offA      = (int*)(W + 355 * sN);                // N+1
    int*   blockSums = (int*)(W + 357 * sN);                // nb
    unsigned short* BT6 = (unsigned short*)(W + 358 * sN);  // 24576 bf16
    float* Wsum = W + 641 * sN;                             // N
    int*   offB = (int*)(W + 642 * sN);                     // N+1
    unsigned short* BTs = (unsigned short*)(W + 644 * sN);          // 8192 bf16
    unsigned short* BTv = (unsigned short*)(W + 644 * sN + 4096);   // 12288 bf16
    float* Tb   = W + 644 * sN + 4096 + 6144;               // 65600 fl
    int2*  SE   = (int2*)(W + 646 * sN);                    // E int2 (32N fl)

    float* outs = (float*)d_out;                            // 64N
    float* outv = outs + 64 * sN;                           // 192N

    hipMemsetAsync(dc, 0, sizeof(float) * 2 * sN, stream);

    deg_cnt_k<<<(E + 255) / 256, 256, 0, stream>>>(edge_index, edge_attr, dc, E);
    scan1_k<<<nb, 1024, 0, stream>>>(dc, blockSums, N);
    scan2_k<<<1, 64, 0, stream>>>(blockSums, nb);
    scan3_k<<<nb, 1024, 0, stream>>>(dc, blockSums, offA, offB, dis, N);
    scatter_k<<<(E + 255) / 256, 256, 0, stream>>>(edge_index, edge_attr, dis, offA, SE, E);

    xbuild_k<<<(N * 64 + 255) / 256, 256, 0, stream>>>(scalar, vector, X, R, N);
    prep_k<<<(24576 + 8192 + 4096 + 8192 + 65600 + 255) / 256, 256, 0, stream>>>(
        Ws2s, Ws2v, Wv2s, Wsl, Wvl, Wv2v, BT6, BTs, BTv, Tb);

    const int mtilesN = (N + 15) / 16;
    node_gemm_k<<<dim3((mtilesN + 3) / 4, 6), 256, 0, stream>>>(
        X, BT6, bs2s, bs2v, bv2s, PC, R, N);

    edge_sorted_k<<<((N + CPW - 1) / CPW + 3) / 4, 256, 0, stream>>>(
        position, dis, PC, R, Tb, SE, offB, Xs, Xv, Wsum, N);

    gemm_s_k<<<(mtilesN + 3) / 4, 256, 0, stream>>>(Xs, BTs, bsl, Wsum, scalar, outs, N);
    const int M = 3 * N;
    gemm_v_k<<<((M + 15) / 16 + 3) / 4, 256, 0, stream>>>(Xv, BTv, vector, outv, M);
}

// Round 6
// 424.356 us; speedup vs baseline: 3.9692x; 1.0367x over previous
//
#include <hip/hip_runtime.h>

// ---------------------------------------------------------------------------
// MolNet layer, round 6:
//   - edge kernel: packed row-gather R2[row][lane][6] (3 dword loads/edge),
//     interleaved RBF LUT T2[s][lane][2] (1 dwordx2/edge), scalar (SGPR) edge
//     metadata, rcp-based activations.
//   - node precompute: single fused MFMA kernel (X read once, 48 MFMA/wave)
//     writing packed PC3 / R2-PR layouts.
//   - launches: memset, deg_cnt, scan1, scan3(+scan2), mid(scatter+xbuild+prep),
//     node_gemm, edge, gemm_sv  (8 total).
// ---------------------------------------------------------------------------

typedef __attribute__((ext_vector_type(8))) short bf16x8;
typedef __attribute__((ext_vector_type(4))) float f32x4;
#define MFMA16(a, b, c) __builtin_amdgcn_mfma_f32_16x16x32_bf16(a, b, c, 0, 0, 0)

__device__ __forceinline__ unsigned short f2bf(float x) {
    union { float f; unsigned u; } v; v.f = x;
    unsigned r = v.u + 0x7FFF + ((v.u >> 16) & 1);
    return (unsigned short)(r >> 16);
}
__device__ __forceinline__ float bf2f(unsigned short h) {
    union { unsigned u; float f; } v; v.u = ((unsigned)h) << 16; return v.f;
}
// low/high bf16 halves of a packed dword -> float
__device__ __forceinline__ float ulo(unsigned u) {
    union { unsigned u; float f; } v; v.u = u << 16; return v.f;
}
__device__ __forceinline__ float uhi(unsigned u) {
    union { unsigned u; float f; } v; v.u = u & 0xffff0000u; return v.f;
}
__device__ __forceinline__ float silu_f(float x) {
    return x * __builtin_amdgcn_rcpf(1.0f + __expf(-x));
}
__device__ __forceinline__ float tanh_f(float x) {
    return 1.0f - 2.0f * __builtin_amdgcn_rcpf(1.0f + __expf(2.0f * x));
}
__device__ __forceinline__ int rfl(int x) { return __builtin_amdgcn_readfirstlane(x); }

// ---------------- sort pipeline --------------------------------------------
__global__ __launch_bounds__(256) void deg_cnt_k(const int* __restrict__ ei,
                                                 const float* __restrict__ attr,
                                                 float* __restrict__ dc, int E) {
    int e = blockIdx.x * 256 + threadIdx.x;
    if (e < E) {
        int col = ei[E + e];
        atomicAdd(&dc[2 * col], attr[e]);
        atomicAdd((int*)dc + 2 * col + 1, 1);
    }
}

__global__ __launch_bounds__(1024) void scan1_k(const float* __restrict__ dc,
                                                int* __restrict__ blockSums, int N) {
    __shared__ int tmp[1024];
    int i = blockIdx.x * 1024 + threadIdx.x;
    tmp[threadIdx.x] = (i < N) ? ((const int*)dc)[2 * i + 1] : 0;
    __syncthreads();
    for (int s = 512; s > 0; s >>= 1) {
        if (threadIdx.x < s) tmp[threadIdx.x] += tmp[threadIdx.x + s];
        __syncthreads();
    }
    if (threadIdx.x == 0) blockSums[blockIdx.x] = tmp[0];
}

// local scan + per-block serial scan of blockSums (scan2 folded in); also dis[]
__global__ __launch_bounds__(1024) void scan3_k(const float* __restrict__ dc,
                                                const int* __restrict__ blockSums,
                                                int* __restrict__ offA,
                                                int* __restrict__ offB,
                                                float* __restrict__ dis, int N) {
    __shared__ int tmp[1024];
    __shared__ int base_s;
    if (threadIdx.x == 0) {
        int b = 0;
        for (int j = 0; j < (int)blockIdx.x; ++j) b += blockSums[j];
        base_s = b;
    }
    int i = blockIdx.x * 1024 + threadIdx.x;
    tmp[threadIdx.x] = (i < N) ? ((const int*)dc)[2 * i + 1] : 0;
    __syncthreads();
    for (int s = 1; s < 1024; s <<= 1) {
        int t = (threadIdx.x >= s) ? tmp[threadIdx.x - s] : 0;
        __syncthreads();
        tmp[threadIdx.x] += t;
        __syncthreads();
    }
    if (i < N) {
        int off = base_s + tmp[threadIdx.x];
        offA[i + 1] = off;
        offB[i + 1] = off;
        float d = dc[2 * i];
        dis[i] = (d > 0.0f) ? rsqrtf(d) : 0.0f;
    }
    if (blockIdx.x == 0 && threadIdx.x == 0) { offA[0] = 0; offB[0] = 0; }
}

// ---------------- fused mid kernel: scatter | xbuild | prep ----------------
// prep index ranges (after E + 64N):
//   [0,24576) BT6 | [24576,32768) BTs | [32768,36864) BTv k<64 |
//   [36864,45056) Aj/Ai | [45056,77888) rbf T2 (513x64)
__global__ __launch_bounds__(256) void mid_k(
    const int* __restrict__ ei, const float* __restrict__ attr,
    const float* __restrict__ dis, int* __restrict__ offA,
    int2* __restrict__ SE, int E,
    const float* __restrict__ scalar, const float* __restrict__ vec,
    unsigned short* __restrict__ X, unsigned short* __restrict__ R2, int N,
    const float* __restrict__ Ws2s, const float* __restrict__ Ws2v,
    const float* __restrict__ Wv2s, const float* __restrict__ Wsl,
    const float* __restrict__ Wvl, const float* __restrict__ Wv2v,
    unsigned short* __restrict__ BT6, unsigned short* __restrict__ BTs,
    unsigned short* __restrict__ BTv, float* __restrict__ T2) {
    int idx = blockIdx.x * 256 + threadIdx.x;
    if (idx < E) {
        int row = ei[idx];
        int col = ei[E + idx];
        int p = atomicAdd(&offA[col], 1);
        SE[p] = make_int2(row, __float_as_int(dis[row] * attr[idx]));
        return;
    }
    idx -= E;
    if (idx < N * 64) {
        int n = idx >> 6, c = idx & 63;
        float v0 = vec[(size_t)n * 192 + c];
        float v1 = vec[(size_t)n * 192 + 64 + c];
        float v2 = vec[(size_t)n * 192 + 128 + c];
        X[(size_t)n * 128 + c] = f2bf(scalar[(size_t)n * 64 + c]);
        X[(size_t)n * 128 + 64 + c] = f2bf(sqrtf(v0 * v0 + v1 * v1 + v2 * v2));
        unsigned short* rw = R2 + (size_t)n * 384 + c * 6;
        rw[3] = f2bf(v0);
        *(unsigned*)(rw + 4) = (unsigned)f2bf(v1) | ((unsigned)f2bf(v2) << 16);
        return;
    }
    idx -= N * 64;
    if (idx < 24576) {
        int y = idx >> 12, n = (idx >> 6) & 63, k = idx & 63;
        const float* W = (y < 2) ? Ws2s : (y < 4) ? Ws2v : Wv2s;
        int kk = (y & 1) ? (64 + k) : k;
        BT6[idx] = f2bf(W[kk * 64 + n]);
    } else if (idx < 32768) {
        int j = idx - 24576;
        int n = j >> 7, k = j & 127;
        BTs[(size_t)n * 128 + k] = f2bf(Wsl[k * 64 + n]);
    } else if (idx < 36864) {
        int j = idx - 32768;
        int n = j >> 6, k = j & 63;
        BTv[(size_t)n * 192 + k] = f2bf(Wvl[(64 + k) * 64 + n]);
    } else if (idx < 45056) {
        int j = idx - 36864;
        int half = j >> 12;            // 0: Aj (row side), 1: Ai (col side)
        int k = (j >> 6) & 63, c = j & 63;
        const float* Wr = Wv2v + (half ? 0 : 64 * 64) + k * 64;
        float acc = 0.0f;
        for (int m = 0; m < 64; ++m) acc += Wr[m] * Wvl[m * 64 + c];
        BTv[(size_t)c * 192 + (half ? 128 : 64) + k] = f2bf(acc);
    } else {
        int j = idx - 45056;
        if (j >= 513 * 64) return;
        int s = j >> 6, c = j & 63;
        float d = (float)s * (6.0f / 512.0f);
        float acc = 0.0f;
        for (int l = 0; l < 50; ++l) {
            float dl = d - 0.10204081632653061f * (float)l;
            acc += __expf(-48.02f * dl * dl) * Wv2s[(128 + l) * 64 + c];
        }
        T2[(s * 64 + c) * 2] = acc;          // pair element 0 of row s
        if (s > 0) T2[((s - 1) * 64 + c) * 2 + 1] = acc;  // element 1 of row s-1
    }
}

// ---------------- fused node precompute GEMM (all 6 projections) -----------
__global__ __launch_bounds__(256) void node_gemm_k(
    const unsigned short* __restrict__ X, const unsigned short* __restrict__ BT6,
    const float* __restrict__ bs2s, const float* __restrict__ bs2v,
    const float* __restrict__ bv2s,
    unsigned short* __restrict__ PC3, unsigned short* __restrict__ R2, int N) {
    const int lane = threadIdx.x & 63;
    const int mtile = blockIdx.x * 4 + (threadIdx.x >> 6);
    const int r0 = mtile * 16;
    if (r0 >= N) return;
    const int quad = lane >> 4, l = lane & 15;
    const int arow = min(r0 + l, N - 1);
    const unsigned short* ap = X + (size_t)arow * 128 + quad * 8;
    bf16x8 as0 = *(const bf16x8*)ap;
    bf16x8 as1 = *(const bf16x8*)(ap + 32);
    bf16x8 av0 = *(const bf16x8*)(ap + 64);
    bf16x8 av1 = *(const bf16x8*)(ap + 96);
    f32x4 acc[6][4];
#pragma unroll
    for (int y = 0; y < 6; ++y) {
        bf16x8 a0 = (y < 4) ? as0 : av0;
        bf16x8 a1 = (y < 4) ? as1 : av1;
        const unsigned short* bp = BT6 + (size_t)y * 4096 + (size_t)l * 64 + quad * 8;
#pragma unroll
        for (int nt = 0; nt < 4; ++nt) {
            acc[y][nt] = (f32x4){0.f, 0.f, 0.f, 0.f};
            bf16x8 b0 = *(const bf16x8*)(bp + nt * 1024);
            bf16x8 b1 = *(const bf16x8*)(bp + nt * 1024 + 32);
            acc[y][nt] = MFMA16(a0, b0, acc[y][nt]);
            acc[y][nt] = MFMA16(a1, b1, acc[y][nt]);
        }
    }
#pragma unroll
    for (int nt = 0; nt < 4; ++nt) {
        int col = nt * 16 + l;
        float b0 = bs2s[col], b1 = bs2v[col], b2 = bv2s[col];
#pragma unroll
        for (int i = 0; i < 4; ++i) {
            int row = r0 + quad * 4 + i;
            if (row < N) {
                unsigned short* pd = PC3 + (size_t)row * 192 + col * 3;
                pd[0] = f2bf(acc[0][nt][i] + b0);
                pd[1] = f2bf(acc[2][nt][i] + b1);
                pd[2] = f2bf(acc[4][nt][i] + b2);
                unsigned short* rd = R2 + (size_t)row * 384 + col * 6;
                *(unsigned*)rd = (unsigned)f2bf(acc[1][nt][i]) |
                                 ((unsigned)f2bf(acc[3][nt][i]) << 16);
                rd[2] = f2bf(acc[5][nt][i]);
            }
        }
    }
}

// ---------------- edge kernel ----------------------------------------------
#define CPW 4
__global__ __launch_bounds__(256) void edge_sorted_k(
    const float* __restrict__ pos, const float* __restrict__ dis,
    const unsigned short* __restrict__ PC3, const unsigned short* __restrict__ R2,
    const float* __restrict__ T2, const int2* __restrict__ SE,
    const int* __restrict__ offB,
    unsigned short* __restrict__ Xs, unsigned short* __restrict__ Xv,
    float* __restrict__ Wsum, int N) {
    const int lane = threadIdx.x & 63;
    const int wave = rfl((blockIdx.x * 256 + threadIdx.x) >> 6);
    const int c0 = wave * CPW;
    const int cend = min(c0 + CPW, N);
    for (int col = c0; col < cend; ++col) {
        const int e0 = rfl(offB[col]);
        const int e1 = rfl(offB[col + 1]);
        const float dcol = dis[col];
        const float px = pos[col * 3], py = pos[col * 3 + 1], pz = pos[col * 3 + 2];
        const unsigned short* pcb = PC3 + (size_t)col * 192 + lane * 3;
        const float pc0 = bf2f(pcb[0]), pc1 = bf2f(pcb[1]), pc2 = bf2f(pcb[2]);
        const unsigned* rc = (const unsigned*)(R2 + (size_t)col * 384 + lane * 6);
        const unsigned cd1 = rc[1], cd2 = rc[2];
        const float wc0 = uhi(cd1), wc1 = ulo(cd2), wc2 = uhi(cd2);
        float a1 = 0, a2 = 0, ws = 0;
        float b30 = 0, b31 = 0, b32 = 0, bv0 = 0, bv1 = 0, bv2 = 0;
        for (int e = e0; e < e1; ++e) {
            const int2 se = SE[e];
            const int row = rfl(se.x);
            const float nrm = dcol * __int_as_float(rfl(se.y));
            const unsigned* rp = (const unsigned*)(R2 + (size_t)row * 384 + lane * 6);
            const unsigned d0 = rp[0], d1 = rp[1], d2 = rp[2];
            const float r0 = px - pos[row * 3 + 0];
            const float r1 = py - pos[row * 3 + 1];
            const float r2 = pz - pos[row * 3 + 2];
            const float dist = sqrtf(r0 * r0 + r1 * r1 + r2 * r2);
            float t = fminf(dist * (512.0f / 6.0f), 511.0f);
            int si = rfl((int)t);
            float fr = t - (float)si;
            float2 tp = *(const float2*)(T2 + (si << 7) + (lane << 1));
            float rbfw = tp.x + fr * (tp.y - tp.x);
            float ss = silu_f(pc0 + ulo(d0));
            float tt = tanh_f(pc1 + uhi(d0));
            float vs = silu_f(pc2 + ulo(d1) + rbfw);
            ws += nrm;
            a1 += nrm * ss;
            a2 += nrm * vs;
            float nt = nrm * tt;
            b30 += nt * r0; b31 += nt * r1; b32 += nt * r2;
            bv0 += nrm * uhi(d1);
            bv1 += nrm * ulo(d2);
            bv2 += nrm * uhi(d2);
        }
        Xs[(size_t)col * 128 + lane] = f2bf(a1);
        Xs[(size_t)col * 128 + 64 + lane] = f2bf(a2);
        const size_t xb = (size_t)col * 576;
        Xv[xb + lane]       = f2bf(b30);
        Xv[xb + 64 + lane]  = f2bf(bv0);
        Xv[xb + 128 + lane] = f2bf(ws * wc0);
        Xv[xb + 192 + lane] = f2bf(b31);
        Xv[xb + 256 + lane] = f2bf(bv1);
        Xv[xb + 320 + lane] = f2bf(ws * wc1);
        Xv[xb + 384 + lane] = f2bf(b32);
        Xv[xb + 448 + lane] = f2bf(bv2);
        Xv[xb + 512 + lane] = f2bf(ws * wc2);
        if (lane == 0) Wsum[col] = ws;
    }
}

// ---------------- fused finalize GEMMs (y=0: scalar, y=1..3: vector) -------
__global__ __launch_bounds__(256) void gemm_sv_k(
    const unsigned short* __restrict__ Xs, const unsigned short* __restrict__ BTs,
    const unsigned short* __restrict__ Xv, const unsigned short* __restrict__ BTv,
    const float* __restrict__ bsl, const float* __restrict__ Wsum,
    const float* __restrict__ scalar, const float* __restrict__ vec,
    float* __restrict__ outs, float* __restrict__ outv, int N) {
    const int y = blockIdx.y;
    const int lane = threadIdx.x & 63;
    const int quad = lane >> 4, l = lane & 15;
    const int wave = threadIdx.x >> 6;
    if (y == 0) {
        const int r0 = (blockIdx.x * 4 + wave) * 16;
        if (r0 >= N) return;
        const int arow = min(r0 + l, N - 1);
        const unsigned short* aptr = Xs + (size_t)arow * 128 + quad * 8;
        bf16x8 a[4];
#pragma unroll
        for (int s = 0; s < 4; ++s) a[s] = *(const bf16x8*)(aptr + s * 32);
        const unsigned short* bptr = BTs + (size_t)l * 128 + quad * 8;
        f32x4 acc[4];
#pragma unroll
        for (int nt = 0; nt < 4; ++nt) {
            acc[nt] = (f32x4){0.f, 0.f, 0.f, 0.f};
#pragma unroll
            for (int s = 0; s < 4; ++s) {
                bf16x8 b = *(const bf16x8*)(bptr + (size_t)nt * 16 * 128 + s * 32);
                acc[nt] = MFMA16(a[s], b, acc[nt]);
            }
        }
#pragma unroll
        for (int nt = 0; nt < 4; ++nt) {
            int col = nt * 16 + l;
            float bc = bsl[col];
#pragma unroll
            for (int i = 0; i < 4; ++i) {
                int row = r0 + quad * 4 + i;
                if (row < N) {
                    float wsn = Wsum[row];
                    outs[(size_t)row * 64 + col] =
                        silu_f(acc[nt][i] + wsn * bc) + scalar[(size_t)row * 64 + col];
                }
            }
        }
    } else {
        const int M = 3 * N;
        const int r0 = ((y - 1) * (N / 16) + blockIdx.x * 4 + wave) * 16;
        if (r0 >= M) return;
        const int arow = min(r0 + l, M - 1);
        const unsigned short* aptr = Xv + (size_t)arow * 192 + quad * 8;
        bf16x8 a[6];
#pragma unroll
        for (int s = 0; s < 6; ++s) a[s] = *(const bf16x8*)(aptr + s * 32);
        const unsigned short* bptr = BTv + (size_t)l * 192 + quad * 8;
        f32x4 acc[4];
#pragma unroll
        for (int nt = 0; nt < 4; ++nt) {
            acc[nt] = (f32x4){0.f, 0.f, 0.f, 0.f};
#pragma unroll
            for (int s = 0; s < 6; ++s) {
                bf16x8 b = *(const bf16x8*)(bptr + (size_t)nt * 16 * 192 + s * 32);
                acc[nt] = MFMA16(a[s], b, acc[nt]);
            }
        }
#pragma unroll
        for (int nt = 0; nt < 4; ++nt) {
            int col = nt * 16 + l;
#pragma unroll
            for (int i = 0; i < 4; ++i) {
                int row = r0 + quad * 4 + i;
                if (row < M)
                    outv[(size_t)row * 64 + col] = acc[nt][i] + vec[(size_t)row * 64 + col];
            }
        }
    }
}

extern "C" void kernel_launch(void* const* d_in, const int* in_sizes, int n_in,
                              void* d_out, int out_size, void* d_ws, size_t ws_size,
                              hipStream_t stream) {
    const float* scalar     = (const float*)d_in[0];
    const float* vector     = (const float*)d_in[1];
    const float* position   = (const float*)d_in[2];
    const int*   edge_index = (const int*)d_in[3];
    const float* edge_attr  = (const float*)d_in[4];
    const float* Ws2s       = (const float*)d_in[5];
    const float* bs2s       = (const float*)d_in[6];
    const float* Wv2s       = (const float*)d_in[7];
    const float* bv2s       = (const float*)d_in[8];
    const float* Wsl        = (const float*)d_in[9];
    const float* bsl        = (const float*)d_in[10];
    const float* Ws2v       = (const float*)d_in[11];
    const float* bs2v       = (const float*)d_in[12];
    const float* Wv2v       = (const float*)d_in[13];
    const float* Wvl        = (const float*)d_in[14];

    const int N = in_sizes[0] / 64;
    const int E = in_sizes[3] / 2;
    const size_t sN = (size_t)N;
    const int nb = (N + 1023) / 1024;

    float* W = (float*)d_ws;
    // float-slot layout with lifetime overlays:
    float*          dis  = W;                                // N
    unsigned short* X    = (unsigned short*)(W + sN);        // 128N ush (64N fl); Xs overlay
    unsigned short* Xs   = X;
    unsigned short* R2   = (unsigned short*)(W + 65 * sN);   // 384N ush [n][64][6]
    unsigned short* PC3  = (unsigned short*)(W + 257 * sN);  // 192N ush [n][64][3]
    unsigned short* Xv   = (unsigned short*)(W + 353 * sN);  // 576N ush
    //   overlays inside Xv region (dead before edge kernel writes Xv):
    float* dc        = W + 353 * sN;                         // 2N
    int*   offA      = (int*)(W + 355 * sN);                 // N+1
    int*   blockSums = (int*)(W + 357 * sN);                 // nb
    unsigned short* BT6 = (unsigned short*)(W + 358 * sN);   // 24576 ush
    float* Wsum = W + 641 * sN;                              // N
    int*   offB = (int*)(W + 642 * sN);                      // N+1
    unsigned short* BTs = (unsigned short*)(W + 644 * sN);          // 8192 ush
    unsigned short* BTv = (unsigned short*)(W + 644 * sN + 4096);   // 12288 ush
    float* T2   = W + 644 * sN + 10240;                      // 513*64*2 fl = 65664
    int2*  SE   = (int2*)(W + 646 * sN);                     // E int2 (32N fl)

    float* outs = (float*)d_out;                             // 64N
    float* outv = outs + 64 * sN;                            // 192N

    hipMemsetAsync(dc, 0, sizeof(float) * 2 * sN, stream);

    deg_cnt_k<<<(E + 255) / 256, 256, 0, stream>>>(edge_index, edge_attr, dc, E);
    scan1_k<<<nb, 1024, 0, stream>>>(dc, blockSums, N);
    scan3_k<<<nb, 1024, 0, stream>>>(dc, blockSums, offA, offB, dis, N);

    const int midTot = E + N * 64 + 45056 + 513 * 64;
    mid_k<<<(midTot + 255) / 256, 256, 0, stream>>>(
        edge_index, edge_attr, dis, offA, SE, E,
        scalar, vector, X, R2, N,
        Ws2s, Ws2v, Wv2s, Wsl, Wvl, Wv2v, BT6, BTs, BTv, T2);

    const int mtilesN = (N + 15) / 16;
    node_gemm_k<<<(mtilesN + 3) / 4, 256, 0, stream>>>(
        X, BT6, bs2s, bs2v, bv2s, PC3, R2, N);

    edge_sorted_k<<<((N + CPW - 1) / CPW + 3) / 4, 256, 0, stream>>>(
        position, dis, PC3, R2, T2, SE, offB, Xs, Xv, Wsum, N);

    gemm_sv_k<<<dim3((mtilesN + 3) / 4, 4), 256, 0, stream>>>(
        Xs, BTs, Xv, BTv, bsl, Wsum, scalar, vector, outs, outv, N);
}